// Round 4
// baseline (368.398 us; speedup 1.0000x reference)
//
#include <hip/hip_runtime.h>
#include <hip/hip_bf16.h>
#include <stdint.h>

// Problem constants
#define B_    16
#define N_    577
#define C_    768
#define H_    12
#define M_    (B_*N_)     // 9232 rows
#define QKVN  (3*C_)      // 2304
#define NKEEP 403         // int(576*0.7)
#define KROWS (NKEEP+1)   // 404
#define VTLD  640         // vtbuf padded row length
#define PTLD  72          // Ptt row stride (ushorts)

typedef short s16x8 __attribute__((ext_vector_type(8)));
typedef float f32x4 __attribute__((ext_vector_type(4)));

__device__ __forceinline__ unsigned short f2bf(float x){
  unsigned int u = __float_as_uint(x);
  u += 0x7FFF + ((u >> 16) & 1);          // round-to-nearest-even
  return (unsigned short)(u >> 16);
}

// async global->LDS, 16B per lane; lds dest = wave-uniform base + lane*16
__device__ __forceinline__ void gld_lds16(const void* g, void* l){
  __builtin_amdgcn_global_load_lds(
      (const __attribute__((address_space(1))) unsigned int*)g,
      (__attribute__((address_space(3))) unsigned int*)l, 16, 0, 0);
}

// Generic XCD-panel tile mapping
template<int NT, int M9, int MTILES>
__device__ __forceinline__ void tile_map(int L, int& mt, int& nt){
  constexpr int NB = MTILES*NT;
  int x = L & 7, j = L >> 3;
  if(j < M9*NT){
    nt = j/M9; mt = x*M9 + (j - nt*M9);    // n-outer: M9 consecutive blocks share B-tile
  } else {
    int offt = 0;
    #pragma unroll
    for(int y=0;y<8;y++) if(y<x) offt += ((NB-1-y)>>3) + 1 - M9*NT;  // tail_y
    int ft = offt + (j - M9*NT);
    mt = 8*M9 + ft/NT;
    nt = ft - (ft/NT)*NT;
  }
}

// ---------------- cast x -> bf16 (vectorized) ----------------
__global__ void k_cvt_x(const float* __restrict__ x, unsigned short* __restrict__ xb){
  int i = blockIdx.x*256 + threadIdx.x;
  float4 v = ((const float4*)x)[i];
  ushort4 o; o.x=f2bf(v.x); o.y=f2bf(v.y); o.z=f2bf(v.z); o.w=f2bf(v.w);
  ((ushort4*)xb)[i] = o;
}

// ------------- transpose+cast weights: out[c][r] = bf16(in[r][c]) -------------
__global__ void k_transpose_cvt(const float* __restrict__ in, unsigned short* __restrict__ out,
                                int R, int CC){
  __shared__ float tile[64][65];
  int r0 = blockIdx.y*64, c0 = blockIdx.x*64;
  int tx = threadIdx.x & 63, ty = threadIdx.x >> 6;
  #pragma unroll
  for(int i=0;i<16;i++){
    int r = ty + i*4;
    tile[r][tx] = in[(size_t)(r0+r)*CC + c0 + tx];
  }
  __syncthreads();
  #pragma unroll
  for(int i=0;i<16;i++){
    int c = ty + i*4;
    out[(size_t)(c0+c)*R + r0 + tx] = f2bf(tile[tx][c]);
  }
}

// =================================================================================
// QKV GEMM (round 4): LDS-FREE streaming GEMM. 128x128 tile, 4 waves, wave-tile
// 64x64, acc 4x4. Rationale (r3 post-mortem): the LDS pipe was the most-loaded
// resource (ds_read 47k + staging-write bursts 31k + 8 conflict-cy/DMA-burst 16k
// ~= 94k of 145k cy/CU) and every k-step paid a full vmcnt(0) drain at a barrier.
// But the MFMA A/B fragment layout (8 consecutive k per lane, 16 rows per
// instruction) is EXACTLY a coalesced global_load_dwordx4 from the row-major
// operands. So: no LDS, no barriers, no drains. Each wave streams its own
// fragments global->VGPR with a 1-step register double-buffer (named X/Y arrays,
// compile-time indexed - rule #20). Twin waves (wm-pairs share B rows, wn-pairs
// share A rows) hit L1; operands are L2/L3-resident (A 14MB, B 3.5MB).
// Accumulation order and operand values identical to r0-r3 -> absmax unchanged.
// V-tiles (n0>=1536) written transposed into vtbuf (FUSEV), rest bf16 into qkvb.
// =================================================================================
__global__ __launch_bounds__(256) void k_gemm_qkv(const unsigned short* __restrict__ A,
                          const unsigned short* __restrict__ Bt,
                          unsigned short* __restrict__ qkvb,
                          unsigned short* __restrict__ vtbuf){
  const int t = threadIdx.x;
  const int w = t>>6, l = t&63, lq = l>>4, lr = l&15;
  const int wm = w>>1, wn = w&1;                        // wave-tile 64x64
  int mt, nt; tile_map<18, 9, 73>(blockIdx.x, mt, nt);
  const int m0 = mt*128, n0 = nt*128;

  // per-lane fragment pointers: row = tile + sub*16 + lr, k-chunk = lq*8
  const unsigned short* pA[4];
  const unsigned short* pB[4];
  #pragma unroll
  for(int mf=0;mf<4;mf++){
    int ra = m0 + wm*64 + mf*16 + lr; if(ra >= M_) ra = M_-1;
    pA[mf] = A + (size_t)ra*768 + lq*8;
  }
  #pragma unroll
  for(int nf=0;nf<4;nf++){
    pB[nf] = Bt + (size_t)(n0 + wn*64 + nf*16 + lr)*768 + lq*8;
  }

  f32x4 acc[4][4] = {};
  s16x8 aX[4], bX[4], aY[4], bY[4];

#define MMA_ALL(AR, BR) do{ \
  _Pragma("unroll") \
  for(int mf_=0;mf_<4;mf_++) \
    _Pragma("unroll") \
    for(int nf_=0;nf_<4;nf_++) \
      acc[mf_][nf_] = __builtin_amdgcn_mfma_f32_16x16x32_bf16(AR[mf_], BR[nf_], acc[mf_][nf_], 0,0,0); \
}while(0)

  // prologue: k-step 0 into X
  #pragma unroll
  for(int i=0;i<4;i++){ aX[i] = *(const s16x8*)(pA[i]); bX[i] = *(const s16x8*)(pB[i]); }

  // 24 k-steps, 2 per iteration; loads for the NEXT step issue before current MFMA
  for(int kp=0; kp<11; ++kp){
    #pragma unroll
    for(int i=0;i<4;i++){ aY[i] = *(const s16x8*)(pA[i]+32); bY[i] = *(const s16x8*)(pB[i]+32); }
    MMA_ALL(aX, bX);                                   // k-step 2*kp
    #pragma unroll
    for(int i=0;i<4;i++){ aX[i] = *(const s16x8*)(pA[i]+64); bX[i] = *(const s16x8*)(pB[i]+64);
                          pA[i] += 64; pB[i] += 64; }
    MMA_ALL(aY, bY);                                   // k-step 2*kp+1
  }
  // tail: k-step 22 in X; load 23 into Y
  #pragma unroll
  for(int i=0;i<4;i++){ aY[i] = *(const s16x8*)(pA[i]+32); bY[i] = *(const s16x8*)(pB[i]+32); }
  MMA_ALL(aX, bX);
  MMA_ALL(aY, bY);
#undef MMA_ALL

  // ---- epilogue: rows m0+wm*64+it*16+lq*4+r, cols n0+wn*64+jt*16+lr
  if(n0 >= 1536){
    // transposed V write: vtbuf[b*768 + (nc-1536)][token], 4 consecutive tokens/lane
    #pragma unroll
    for(int it=0;it<4;it++){
      int tok0 = m0 + wm*64 + it*16 + lq*4;
      #pragma unroll
      for(int jt=0;jt<4;jt++){
        int vrow = (n0 - 1536) + wn*64 + jt*16 + lr;
        ushort4 pk; unsigned short* pks = (unsigned short*)&pk;
        #pragma unroll
        for(int r=0;r<4;r++) pks[r] = f2bf(acc[it][jt][r]);
        int b0 = tok0/577, t0 = tok0 - b0*577;
        if(tok0 + 3 < M_ && t0 + 3 < 577){
          *(ushort4*)&vtbuf[(size_t)(b0*768 + vrow)*VTLD + t0] = pk;
        } else {
          #pragma unroll
          for(int r=0;r<4;r++){
            int tg = tok0 + r;
            if(tg < M_){
              int bb = tg/577, tt = tg - bb*577;
              vtbuf[(size_t)(bb*768 + vrow)*VTLD + tt] = pks[r];
            }
          }
        }
      }
    }
  } else {
    #pragma unroll
    for(int it=0;it<4;it++){
      #pragma unroll
      for(int r=0;r<4;r++){
        int row = m0 + wm*64 + it*16 + lq*4 + r;
        if(row < M_){
          #pragma unroll
          for(int jt=0;jt<4;jt++){
            int col = n0 + wn*64 + jt*16 + lr;
            qkvb[(size_t)row*2304 + col] = f2bf(acc[it][jt][r]);
          }
        }
      }
    }
  }
}

// ---------------- bf16 MFMA GEMM, 64x128 tile (for parallelism-starved GEMM2) ----------------
// wave-tile 32x64 (acc 2x4 = 32 AGPR). f32 out + bias.
__global__ __launch_bounds__(256) void k_gemm_bt64(const unsigned short* __restrict__ A,
                          const unsigned short* __restrict__ Bt,
                          float* __restrict__ Cout,
                          const float* __restrict__ bias, int Mdim){
  __shared__ __align__(16) unsigned short As[64*32];    // 4 KB
  __shared__ __align__(16) unsigned short Bs[128*32];   // 8 KB
  const int t = threadIdx.x;
  const int w = t>>6, l = t&63, lq = l>>4, lr = l&15;
  const int wm = w>>1, wn = w&1;                        // wave-tile rows wm*32, cols wn*64
  int mt, nt; tile_map<6, 18, 145>(blockIdx.x, mt, nt);
  const int m0 = mt*64, n0 = nt*128;
  int rA0 = m0 + (t>>2);       if(rA0 >= Mdim) rA0 = Mdim-1;
  const unsigned short* gA0 = A  + (size_t)rA0*768 + (t&3)*8;
  const unsigned short* gB0 = Bt + (size_t)(n0 + (t>>2))*768 + (t&3)*8;
  const unsigned short* gB1 = Bt + (size_t)(n0 + ((t+256)>>2))*768 + (t&3)*8;
  unsigned short* lA0 = As + (size_t)w*512;
  unsigned short* lB0 = Bs + (size_t)w*512;
  unsigned short* lB1 = Bs + 2048 + (size_t)w*512;
  f32x4 acc[2][4] = {};
  for(int kt=0; kt<24; ++kt){
    const int ko = kt*32;
    __syncthreads();
    gld_lds16(gA0 + ko, lA0);
    gld_lds16(gB0 + ko, lB0); gld_lds16(gB1 + ko, lB1);
    __syncthreads();
    s16x8 af[2], bfr[4];
    #pragma unroll
    for(int it=0;it<2;it++) af[it]  = *(const s16x8*)&As[(wm*32+it*16+lr)*32 + lq*8];
    #pragma unroll
    for(int jt=0;jt<4;jt++) bfr[jt] = *(const s16x8*)&Bs[(wn*64+jt*16+lr)*32 + lq*8];
    #pragma unroll
    for(int it=0;it<2;it++)
      #pragma unroll
      for(int jt=0;jt<4;jt++)
        acc[it][jt] = __builtin_amdgcn_mfma_f32_16x16x32_bf16(af[it], bfr[jt], acc[it][jt], 0,0,0);
  }
  #pragma unroll
  for(int it=0;it<2;it++){
    #pragma unroll
    for(int r=0;r<4;r++){
      int row = m0 + wm*32 + it*16 + lq*4 + r;
      if(row < Mdim){
        #pragma unroll
        for(int jt=0;jt<4;jt++){
          int col = n0 + wn*64 + jt*16 + lr;
          Cout[(size_t)row*768 + col] = acc[it][jt][r] + bias[col];
        }
      }
    }
  }
}

// ---------------- fused flash attention, max-free softmax, S^T, peeled edge tile ----------------
__global__ __launch_bounds__(256,4) void k_attn(const unsigned short* __restrict__ qkv,
                                                const unsigned short* __restrict__ vtbuf,
                                                unsigned short* __restrict__ aout){
  __shared__ __align__(16) unsigned short Ks[64*64];
  __shared__ __align__(16) unsigned short Vt[64*64];
  __shared__ __align__(16) unsigned short Ptt[128*PTLD];
  __shared__ float Ls[4][2][16][4];
  const int blk = blockIdx.x;
  const int bh = blk % 192, qt = blk / 192;
  const int b = bh / 12, h = bh % 12;
  const int t = threadIdx.x, w = t>>6, l = t&63, lq = l>>4, lr = l&15;
  const size_t base = (size_t)(b*577)*2304 + h*64;
  const int q0 = qt*128;
  s16x8 bq[2][2];
  #pragma unroll
  for(int it=0;it<2;it++){
    int qrow = q0 + w*32 + it*16 + lr; if(qrow > 576) qrow = 576;
    #pragma unroll
    for(int ks=0;ks<2;ks++)
      bq[it][ks] = *(const s16x8*)&qkv[base + (size_t)qrow*2304 + ks*32 + lq*8];
  }
  const int srow = w*8 + (l>>3);
  const int cswz8 = (((l&7) ^ (l>>3)) << 3);
  unsigned short* ldsK = Ks + (size_t)w*512;
  unsigned short* ldsV = Vt + (size_t)w*512;
  const unsigned short* gVbase = vtbuf + (size_t)(bh*64)*VTLD + cswz8;

  f32x4 acc_o[2][4] = {};
  float lsum[2] = {0.f, 0.f};
  const float CEXP = 0.18033688011112043f;              // 0.125 * log2(e)

  auto tile_body = [&](int j0, bool edge){
    __syncthreads();
    #pragma unroll
    for(int i=0;i<2;i++){
      int krow = j0 + i*32 + srow; if(krow > 576) krow = 576;
      gld_lds16(qkv + base + 768 + (size_t)krow*2304 + cswz8, ldsK + i*2048);
      gld_lds16(gVbase + (size_t)(i*32 + srow)*VTLD + j0,     ldsV + i*2048);
    }
    __syncthreads();
    f32x4 accs[2][4] = {};
    #pragma unroll
    for(int ks=0;ks<2;ks++){
      s16x8 ak[4];
      #pragma unroll
      for(int jt=0;jt<4;jt++){
        int j = jt*16 + lr;
        ak[jt] = *(const s16x8*)&Ks[j*64 + (((4*ks+lq) ^ (j&7))<<3)];
      }
      #pragma unroll
      for(int it=0;it<2;it++)
        #pragma unroll
        for(int jt=0;jt<4;jt++)
          accs[it][jt] = __builtin_amdgcn_mfma_f32_16x16x32_bf16(ak[jt], bq[it][ks], accs[it][jt], 0,0,0);
    }
    #pragma unroll
    for(int it=0;it<2;it++){
      int qlocal = w*32 + it*16 + lr;
      #pragma unroll
      for(int jt=0;jt<4;jt++){
        ushort4 pk;
        unsigned short* pks = (unsigned short*)&pk;
        #pragma unroll
        for(int r=0;r<4;r++){
          float p = exp2f(accs[it][jt][r] * CEXP);
          if(edge){ if(j0 + jt*16 + lq*4 + r > 576) p = 0.f; }
          lsum[it] += p;
          pks[r] = f2bf(p);
        }
        *(ushort4*)&Ptt[qlocal*PTLD + jt*16 + lq*4] = pk;
      }
    }
    #pragma unroll
    for(int ks=0;ks<2;ks++){
      s16x8 ap[2], bv[4];
      #pragma unroll
      for(int it=0;it<2;it++)
        ap[it] = *(const s16x8*)&Ptt[(w*32+it*16+lr)*PTLD + ks*32 + lq*8];
      #pragma unroll
      for(int dt=0;dt<4;dt++){
        int d = dt*16 + lr;
        bv[dt] = *(const s16x8*)&Vt[d*64 + (((4*ks+lq) ^ (d&7))<<3)];
      }
      #pragma unroll
      for(int it=0;it<2;it++)
        #pragma unroll
        for(int dt=0;dt<4;dt++)
          acc_o[it][dt] = __builtin_amdgcn_mfma_f32_16x16x32_bf16(ap[it], bv[dt], acc_o[it][dt], 0,0,0);
    }
  };
  for(int j0=0; j0<576; j0+=64) tile_body(j0, false);   // j <= 575: no masking needed
  tile_body(576, true);                                 // edge tile: only j=576 valid

  #pragma unroll
  for(int it=0;it<2;it++) Ls[w][it][lr][lq] = lsum[it];
  #pragma unroll
  for(int it=0;it<2;it++){
    #pragma unroll
    for(int r=0;r<4;r++){
      int n = q0 + w*32 + it*16 + lq*4 + r;
      if(n <= 576){
        int q16 = lq*4 + r;
        float lt = Ls[w][it][q16][0] + Ls[w][it][q16][1] + Ls[w][it][q16][2] + Ls[w][it][q16][3];
        float inv = 1.f / lt;
        #pragma unroll
        for(int dt=0;dt<4;dt++)
          aout[(size_t)(b*577+n)*768 + h*64 + dt*16 + lr] = f2bf(acc_o[it][dt][r]*inv);
      }
    }
  }
}

// ---------------- fp32 top-k path (exact ranking) ----------------
__global__ void k_qcls(const float* __restrict__ x, const float* __restrict__ Wqkv,
                       float* __restrict__ qcls){
  __shared__ float xs[768];
  __shared__ float part[4][64];
  const int b = blockIdx.y, j0 = blockIdx.x*64;
  const int t = threadIdx.x;
  const float* xr = x + (size_t)b*577*768;
  xs[t] = xr[t]; xs[t+256] = xr[t+256]; xs[t+512] = xr[t+512];
  __syncthreads();
  const int jl = t & 63, cs = t >> 6;
  float acc = 0.f;
  const float* wp = Wqkv + (size_t)(cs*192)*2304 + j0 + jl;
  #pragma unroll 4
  for(int c=0;c<192;c++){ acc += xs[cs*192+c] * wp[0]; wp += 2304; }
  part[cs][jl] = acc;
  __syncthreads();
  if(t < 64) qcls[b*768 + j0 + t] = part[0][t]+part[1][t]+part[2][t]+part[3][t];
}
__global__ void k_u(const float* __restrict__ Wqkv, const float* __restrict__ qcls,
                    float* __restrict__ u){
  int h = blockIdx.x, b = blockIdx.y, c = threadIdx.x;  // 768 threads
  const float* qc = qcls + b*768 + h*64;
  const float* wr = Wqkv + (size_t)c*2304 + 768 + h*64;
  float acc = 0.f;
  #pragma unroll
  for(int d=0;d<64;d++) acc += wr[d]*qc[d];
  u[(size_t)(b*12+h)*768 + c] = acc;
}
__global__ void k_attw(const float* __restrict__ x, const float* __restrict__ u,
                       float* __restrict__ attw){
  int blk = blockIdx.x;               // 16*577 blocks of 1 wave
  int b = blk/577, m = blk%577;
  int lane = threadIdx.x;
  const float* xr = x + (size_t)(b*577+m)*768;
  const float* ub = u + (size_t)b*12*768;
  float part[12];
  #pragma unroll
  for(int h=0;h<12;h++) part[h]=0.f;
  #pragma unroll
  for(int i=0;i<12;i++){
    float xv = xr[i*64 + lane];
    #pragma unroll
    for(int h=0;h<12;h++) part[h] += xv * ub[h*768 + i*64 + lane];
  }
  float s = 0.f;
  #pragma unroll
  for(int h=0;h<12;h++){
    float v = part[h];
    #pragma unroll
    for(int off=32; off; off>>=1) v += __shfl_xor(v, off);
    s += fabsf(v);
  }
  if(lane==0) attw[b*577 + m] = 0.125f * s;
}
__global__ void k_topk(const float* __restrict__ attw, int* __restrict__ idxbuf){
  __shared__ float sw[576];
  __shared__ int wtot[9];
  int b = blockIdx.x, t = threadIdx.x;     // 576 threads
  float wv = attw[b*577 + 1 + t];
  sw[t] = wv;
  __syncthreads();
  int rank = 0;
  for(int j=0;j<576;j++){
    float wj = sw[j];
    rank += (wj > wv) || (wj == wv && j < t);
  }
  bool kept = rank < NKEEP;
  unsigned long long mask = __ballot(kept);
  int wid = t>>6, lane = t&63;
  int pos = __popcll(mask & ((1ull<<lane)-1ull));
  if(lane==0) wtot[wid] = __popcll(mask);
  __syncthreads();
  int off0 = 0;
  for(int q=0;q<wid;q++) off0 += wtot[q];
  if(kept) idxbuf[b*KROWS + 1 + off0 + pos] = t+1;
  if(t==0) idxbuf[b*KROWS] = 0;
}
__global__ void k_fill_keep(const int* __restrict__ idxbuf, float* __restrict__ out2){
  int i4 = blockIdx.x*256 + threadIdx.x;
  float v = (float)idxbuf[i4/192];
  ((float4*)out2)[i4] = make_float4(v,v,v,v);
}

extern "C" void kernel_launch(void* const* d_in, const int* in_sizes, int n_in,
                              void* d_out, int out_size, void* d_ws, size_t ws_size,
                              hipStream_t stream){
  const float* x     = (const float*)d_in[0];
  const float* Wqkv  = (const float*)d_in[1];
  const float* Wproj = (const float*)d_in[2];
  const float* bias  = (const float*)d_in[3];
  float* out  = (float*)d_out;
  float* out2 = out + (size_t)M_*768;      // keep_index chunk (float32)

  char* ws = (char*)d_ws;
  size_t off = 0;
  auto alloc = [&](size_t bytes)->void*{ void* p = ws + off; off += (bytes + 255) & ~(size_t)255; return p; };
  unsigned short* xb     = (unsigned short*)alloc((size_t)M_*768*2);
  unsigned short* wqkvT  = (unsigned short*)alloc((size_t)QKVN*768*2);
  unsigned short* wprojT = (unsigned short*)alloc((size_t)768*768*2);
  unsigned short* qkvb   = (unsigned short*)alloc((size_t)M_*QKVN*2);
  unsigned short* aoutb  = (unsigned short*)alloc((size_t)M_*768*2);
  unsigned short* vtbuf  = (unsigned short*)alloc((size_t)192*64*VTLD*2);
  float* qcls   = (float*)alloc((size_t)16*768*4);
  float* u      = (float*)alloc((size_t)16*12*768*4);
  float* attw   = (float*)alloc((size_t)16*577*4);
  int*   idxbuf = (int*)alloc((size_t)16*KROWS*4);

  // bf16 casts / transposes
  k_cvt_x<<<6924, 256, 0, stream>>>(x, xb);
  k_transpose_cvt<<<dim3(36,12), 256, 0, stream>>>(Wqkv,  wqkvT, 768, 2304);
  k_transpose_cvt<<<dim3(12,12), 256, 0, stream>>>(Wproj, wprojT, 768, 768);
  // QKV GEMM (bf16 out; V-tiles written transposed into vtbuf). LDS-free streaming.
  k_gemm_qkv<<<73*18, 256, 0, stream>>>(xb, wqkvT, qkvb, vtbuf);
  // fp32 top-k weight path
  k_qcls<<<dim3(12,16), 256, 0, stream>>>(x, Wqkv, qcls);
  k_u<<<dim3(12,16), 768, 0, stream>>>(Wqkv, qcls, u);
  k_attw<<<16*577, 64, 0, stream>>>(x, u, attw);
  k_topk<<<16, 576, 0, stream>>>(attw, idxbuf);
  k_fill_keep<<<(16*KROWS*768/4 + 255)/256, 256, 0, stream>>>(idxbuf, out2);
  // attention + out-proj
  k_attn<<<960, 256, 0, stream>>>(qkvb, vtbuf, aoutb);
  k_gemm_bt64<<<145*6, 256, 0, stream>>>(aoutb, wprojT, out, bias, M_);
}

// Round 5
// 281.441 us; speedup vs baseline: 1.3090x; 1.3090x over previous
//
#include <hip/hip_runtime.h>
#include <hip/hip_bf16.h>
#include <stdint.h>

// Problem constants
#define B_    16
#define N_    577
#define C_    768
#define H_    12
#define M_    (B_*N_)     // 9232 rows
#define QKVN  (3*C_)      // 2304
#define NKEEP 403         // int(576*0.7)
#define KROWS (NKEEP+1)   // 404
#define VTLD  640         // vtbuf padded row length
#define PTLD  72          // Ptt row stride (ushorts)

typedef short s16x8 __attribute__((ext_vector_type(8)));
typedef float f32x4 __attribute__((ext_vector_type(4)));

__device__ __forceinline__ unsigned short f2bf(float x){
  unsigned int u = __float_as_uint(x);
  u += 0x7FFF + ((u >> 16) & 1);          // round-to-nearest-even
  return (unsigned short)(u >> 16);
}

// async global->LDS, 16B per lane; lds dest = wave-uniform base + lane*16
__device__ __forceinline__ void gld_lds16(const void* g, void* l){
  __builtin_amdgcn_global_load_lds(
      (const __attribute__((address_space(1))) unsigned int*)g,
      (__attribute__((address_space(3))) unsigned int*)l, 16, 0, 0);
}

// Generic XCD-panel tile mapping: xcd = L&7 owns m-panel [x*M9, x*M9+M9);
// tail m-tiles (>= 8*M9) distributed to match round-robin per-XCD counts (bijective).
template<int NT, int M9, int MTILES>
__device__ __forceinline__ void tile_map(int L, int& mt, int& nt){
  constexpr int NB = MTILES*NT;
  int x = L & 7, j = L >> 3;
  if(j < M9*NT){
    nt = j/M9; mt = x*M9 + (j - nt*M9);    // n-outer: M9 consecutive blocks share B-tile
  } else {
    int offt = 0;
    #pragma unroll
    for(int y=0;y<8;y++) if(y<x) offt += ((NB-1-y)>>3) + 1 - M9*NT;  // tail_y
    int ft = offt + (j - M9*NT);
    mt = 8*M9 + ft/NT;
    nt = ft - (ft/NT)*NT;
  }
}

// ---------------- cast x -> bf16 (vectorized) ----------------
__global__ void k_cvt_x(const float* __restrict__ x, unsigned short* __restrict__ xb){
  int i = blockIdx.x*256 + threadIdx.x;
  float4 v = ((const float4*)x)[i];
  ushort4 o; o.x=f2bf(v.x); o.y=f2bf(v.y); o.z=f2bf(v.z); o.w=f2bf(v.w);
  ((ushort4*)xb)[i] = o;
}

// ------------- transpose+cast weights: out[c][r] = bf16(in[r][c]) -------------
__global__ void k_transpose_cvt(const float* __restrict__ in, unsigned short* __restrict__ out,
                                int R, int CC){
  __shared__ float tile[64][65];
  int r0 = blockIdx.y*64, c0 = blockIdx.x*64;
  int tx = threadIdx.x & 63, ty = threadIdx.x >> 6;
  #pragma unroll
  for(int i=0;i<16;i++){
    int r = ty + i*4;
    tile[r][tx] = in[(size_t)(r0+r)*CC + c0 + tx];
  }
  __syncthreads();
  #pragma unroll
  for(int i=0;i<16;i++){
    int c = ty + i*4;
    out[(size_t)(c0+c)*R + r0 + tx] = f2bf(tile[tx][c]);
  }
}

// ---------------- bf16 MFMA GEMM, 128x128 tile (round-0 form, FROZEN best: 60.4us) ----------------
// r0-r4 post-mortems: 8-phase 256^2 (71us), fixed-swizzle (71us), dbuf 2blk/CU (66us),
// LDS-free streaming (148us - fragment loads are lane-strided, uncoalesced) all lose
// to this simple 2-barrier form at K=768/128^2. Frozen.
template<int LDC_, bool BF16OUT, bool FUSEV, int NT>
__global__ __launch_bounds__(256) void k_gemm_bt(const unsigned short* __restrict__ A,
                          const unsigned short* __restrict__ Bt,
                          void* __restrict__ Cout,
                          const float* __restrict__ bias, int Mdim,
                          unsigned short* __restrict__ vtbuf){
  __shared__ __align__(16) unsigned short As[128*32];
  __shared__ __align__(16) unsigned short Bs[128*32];
  const int t = threadIdx.x;
  const int w = t>>6, l = t&63, lq = l>>4, lr = l&15;
  const int wm = w>>1, wn = w&1;
  int mt, nt; tile_map<NT, 9, 73>(blockIdx.x, mt, nt);
  const int m0 = mt*128, n0 = nt*128;
  int rA0 = m0 + (t>>2);       if(rA0 >= Mdim) rA0 = Mdim-1;
  int rA1 = m0 + ((t+256)>>2); if(rA1 >= Mdim) rA1 = Mdim-1;
  const unsigned short* gA0 = A  + (size_t)rA0*768 + (t&3)*8;
  const unsigned short* gA1 = A  + (size_t)rA1*768 + (t&3)*8;
  const unsigned short* gB0 = Bt + (size_t)(n0 + (t>>2))*768 + (t&3)*8;
  const unsigned short* gB1 = Bt + (size_t)(n0 + ((t+256)>>2))*768 + (t&3)*8;
  unsigned short* lA0 = As + (size_t)w*512;
  unsigned short* lA1 = As + 2048 + (size_t)w*512;
  unsigned short* lB0 = Bs + (size_t)w*512;
  unsigned short* lB1 = Bs + 2048 + (size_t)w*512;
  f32x4 acc[4][4] = {};
  for(int kt=0; kt<24; ++kt){
    const int ko = kt*32;
    __syncthreads();
    gld_lds16(gA0 + ko, lA0); gld_lds16(gA1 + ko, lA1);
    gld_lds16(gB0 + ko, lB0); gld_lds16(gB1 + ko, lB1);
    __syncthreads();
    s16x8 af[4], bfr[4];
    #pragma unroll
    for(int it=0;it<4;it++) af[it]  = *(const s16x8*)&As[(wm*64+it*16+lr)*32 + lq*8];
    #pragma unroll
    for(int jt=0;jt<4;jt++) bfr[jt] = *(const s16x8*)&Bs[(wn*64+jt*16+lr)*32 + lq*8];
    #pragma unroll
    for(int it=0;it<4;it++)
      #pragma unroll
      for(int jt=0;jt<4;jt++)
        acc[it][jt] = __builtin_amdgcn_mfma_f32_16x16x32_bf16(af[it], bfr[jt], acc[it][jt], 0,0,0);
  }
  if(FUSEV && n0 >= 1536){
    // transposed V write: vtbuf[b*768 + (nc-1536)][token], 4 consecutive tokens/lane
    #pragma unroll
    for(int it=0;it<4;it++){
      int tok0 = m0 + wm*64 + it*16 + lq*4;      // global row of r=0
      #pragma unroll
      for(int jt=0;jt<4;jt++){
        int vrow = (n0 - 1536) + wn*64 + jt*16 + lr;
        ushort4 pk; unsigned short* pks = (unsigned short*)&pk;
        #pragma unroll
        for(int r=0;r<4;r++) pks[r] = f2bf(acc[it][jt][r]);
        int b0 = tok0/577, t0 = tok0 - b0*577;
        if(tok0 + 3 < M_ && t0 + 3 < 577){
          *(ushort4*)&vtbuf[(size_t)(b0*768 + vrow)*VTLD + t0] = pk;
        } else {
          #pragma unroll
          for(int r=0;r<4;r++){
            int tg = tok0 + r;
            if(tg < M_){
              int bb = tg/577, tt = tg - bb*577;
              vtbuf[(size_t)(bb*768 + vrow)*VTLD + tt] = pks[r];
            }
          }
        }
      }
    }
  } else {
    #pragma unroll
    for(int it=0;it<4;it++){
      #pragma unroll
      for(int r=0;r<4;r++){
        int row = m0 + wm*64 + it*16 + lq*4 + r;
        if(row < Mdim){
          #pragma unroll
          for(int jt=0;jt<4;jt++){
            int col = n0 + wn*64 + jt*16 + lr;
            float v = acc[it][jt][r];
            if constexpr (BF16OUT)
              ((unsigned short*)Cout)[(size_t)row*LDC_ + col] = f2bf(v);
            else
              ((float*)Cout)[(size_t)row*LDC_ + col] = v + bias[col];
          }
        }
      }
    }
  }
}

// ---------------- bf16 MFMA GEMM, 64x128 tile (for parallelism-starved GEMM2) ----------------
// wave-tile 32x64 (acc 2x4 = 32 AGPR). f32 out + bias.
__global__ __launch_bounds__(256) void k_gemm_bt64(const unsigned short* __restrict__ A,
                          const unsigned short* __restrict__ Bt,
                          float* __restrict__ Cout,
                          const float* __restrict__ bias, int Mdim){
  __shared__ __align__(16) unsigned short As[64*32];    // 4 KB
  __shared__ __align__(16) unsigned short Bs[128*32];   // 8 KB
  const int t = threadIdx.x;
  const int w = t>>6, l = t&63, lq = l>>4, lr = l&15;
  const int wm = w>>1, wn = w&1;                        // wave-tile rows wm*32, cols wn*64
  int mt, nt; tile_map<6, 18, 145>(blockIdx.x, mt, nt);
  const int m0 = mt*64, n0 = nt*128;
  int rA0 = m0 + (t>>2);       if(rA0 >= Mdim) rA0 = Mdim-1;
  const unsigned short* gA0 = A  + (size_t)rA0*768 + (t&3)*8;
  const unsigned short* gB0 = Bt + (size_t)(n0 + (t>>2))*768 + (t&3)*8;
  const unsigned short* gB1 = Bt + (size_t)(n0 + ((t+256)>>2))*768 + (t&3)*8;
  unsigned short* lA0 = As + (size_t)w*512;
  unsigned short* lB0 = Bs + (size_t)w*512;
  unsigned short* lB1 = Bs + 2048 + (size_t)w*512;
  f32x4 acc[2][4] = {};
  for(int kt=0; kt<24; ++kt){
    const int ko = kt*32;
    __syncthreads();
    gld_lds16(gA0 + ko, lA0);
    gld_lds16(gB0 + ko, lB0); gld_lds16(gB1 + ko, lB1);
    __syncthreads();
    s16x8 af[2], bfr[4];
    #pragma unroll
    for(int it=0;it<2;it++) af[it]  = *(const s16x8*)&As[(wm*32+it*16+lr)*32 + lq*8];
    #pragma unroll
    for(int jt=0;jt<4;jt++) bfr[jt] = *(const s16x8*)&Bs[(wn*64+jt*16+lr)*32 + lq*8];
    #pragma unroll
    for(int it=0;it<2;it++)
      #pragma unroll
      for(int jt=0;jt<4;jt++)
        acc[it][jt] = __builtin_amdgcn_mfma_f32_16x16x32_bf16(af[it], bfr[jt], acc[it][jt], 0,0,0);
  }
  #pragma unroll
  for(int it=0;it<2;it++){
    #pragma unroll
    for(int r=0;r<4;r++){
      int row = m0 + wm*32 + it*16 + lq*4 + r;
      if(row < Mdim){
        #pragma unroll
        for(int jt=0;jt<4;jt++){
          int col = n0 + wn*64 + jt*16 + lr;
          Cout[(size_t)row*768 + col] = acc[it][jt][r] + bias[col];
        }
      }
    }
  }
}

// ---------------- fused flash attention (round 5: T14 async-STAGE split) ----------------
// Previous form: per tile {sync; global_load_lds x4; sync} - the second sync forces a
// full vmcnt(0) drain, exposing K/V load latency serially 10x per block.
// T14: load tile g+1 global->REGS right after the post-write barrier (covered by the
// whole compute of tile g), ds_write them at the top of iteration g+1. Barriers are raw
// s_barrier + lgkmcnt(0) only (no vmcnt drain) so in-flight loads survive the barrier.
// LDS layout/swizzles/addresses byte-identical to the DMA version -> same math/absmax.
__global__ __launch_bounds__(256,4) void k_attn(const unsigned short* __restrict__ qkv,
                                                const unsigned short* __restrict__ vtbuf,
                                                unsigned short* __restrict__ aout){
  __shared__ __align__(16) unsigned short Ks[64*64];
  __shared__ __align__(16) unsigned short Vt[64*64];
  __shared__ __align__(16) unsigned short Ptt[128*PTLD];
  __shared__ float Ls[4][2][16][4];
  const int blk = blockIdx.x;
  const int bh = blk % 192, qt = blk / 192;
  const int b = bh / 12, h = bh % 12;
  const int t = threadIdx.x, w = t>>6, l = t&63, lq = l>>4, lr = l&15;
  const size_t base = (size_t)(b*577)*2304 + h*64;
  const int q0 = qt*128;
  s16x8 bq[2][2];
  #pragma unroll
  for(int it=0;it<2;it++){
    int qrow = q0 + w*32 + it*16 + lr; if(qrow > 576) qrow = 576;
    #pragma unroll
    for(int ks=0;ks<2;ks++)
      bq[it][ks] = *(const s16x8*)&qkv[base + (size_t)qrow*2304 + ks*32 + lq*8];
  }
  const int srow = w*8 + (l>>3);
  const int cswz8 = (((l&7) ^ (l>>3)) << 3);
  // ds_write dest: same bytes the DMA wrote: wave base (w*1024B) + i*4096B + lane*16B
  unsigned short* ldsK = Ks + w*512 + l*8;
  unsigned short* ldsV = Vt + w*512 + l*8;
  const unsigned short* gVbase = vtbuf + (size_t)(bh*64)*VTLD + cswz8;

  f32x4 acc_o[2][4] = {};
  float lsum[2] = {0.f, 0.f};
  const float CEXP = 0.18033688011112043f;              // 0.125 * log2(e)

  // named stage registers (rule #20: compile-time indexed)
  s16x8 kreg0, kreg1, vreg0, vreg1;
  auto stage_issue = [&](int tt){
    const int j0i = tt*64;
    int kr0 = j0i + srow;      if(kr0 > 576) kr0 = 576;
    int kr1 = j0i + 32 + srow; if(kr1 > 576) kr1 = 576;
    kreg0 = *(const s16x8*)(qkv + base + 768 + (size_t)kr0*2304 + cswz8);
    kreg1 = *(const s16x8*)(qkv + base + 768 + (size_t)kr1*2304 + cswz8);
    vreg0 = *(const s16x8*)(gVbase + (size_t)srow*VTLD + j0i);
    vreg1 = *(const s16x8*)(gVbase + (size_t)(32 + srow)*VTLD + j0i);
  };

  stage_issue(0);
  for(int g=0; g<10; ++g){
    const int j0 = g*64;
    const bool edge = (g == 9);                         // only j<=576 valid in tile 9
    // write staged regs (compiler inserts the vmcnt wait on kreg/vreg use)
    *(s16x8*)(ldsK)        = kreg0;
    *(s16x8*)(ldsK + 2048) = kreg1;
    *(s16x8*)(ldsV)        = vreg0;
    *(s16x8*)(ldsV + 2048) = vreg1;
    asm volatile("s_waitcnt lgkmcnt(0)" ::: "memory");  // all my ds_writes done
    __builtin_amdgcn_s_barrier();                       // tile g visible block-wide
    __builtin_amdgcn_sched_barrier(0);
    if(g < 9) stage_issue(g+1);                         // overlaps compute of tile g

    f32x4 accs[2][4] = {};
    #pragma unroll
    for(int ks=0;ks<2;ks++){
      s16x8 ak[4];
      #pragma unroll
      for(int jt=0;jt<4;jt++){
        int j = jt*16 + lr;
        ak[jt] = *(const s16x8*)&Ks[j*64 + (((4*ks+lq) ^ (j&7))<<3)];
      }
      #pragma unroll
      for(int it=0;it<2;it++)
        #pragma unroll
        for(int jt=0;jt<4;jt++)
          accs[it][jt] = __builtin_amdgcn_mfma_f32_16x16x32_bf16(ak[jt], bq[it][ks], accs[it][jt], 0,0,0);
    }
    #pragma unroll
    for(int it=0;it<2;it++){
      int qlocal = w*32 + it*16 + lr;
      #pragma unroll
      for(int jt=0;jt<4;jt++){
        ushort4 pk;
        unsigned short* pks = (unsigned short*)&pk;
        #pragma unroll
        for(int r=0;r<4;r++){
          float p = exp2f(accs[it][jt][r] * CEXP);
          if(edge){ if(j0 + jt*16 + lq*4 + r > 576) p = 0.f; }
          lsum[it] += p;
          pks[r] = f2bf(p);
        }
        *(ushort4*)&Ptt[qlocal*PTLD + jt*16 + lq*4] = pk;
      }
    }
    #pragma unroll
    for(int ks=0;ks<2;ks++){
      s16x8 ap[2], bv[4];
      #pragma unroll
      for(int it=0;it<2;it++)
        ap[it] = *(const s16x8*)&Ptt[(w*32+it*16+lr)*PTLD + ks*32 + lq*8];
      #pragma unroll
      for(int dt=0;dt<4;dt++){
        int d = dt*16 + lr;
        bv[dt] = *(const s16x8*)&Vt[d*64 + (((4*ks+lq) ^ (d&7))<<3)];
      }
      #pragma unroll
      for(int it=0;it<2;it++)
        #pragma unroll
        for(int dt=0;dt<4;dt++)
          acc_o[it][dt] = __builtin_amdgcn_mfma_f32_16x16x32_bf16(ap[it], bv[dt], acc_o[it][dt], 0,0,0);
    }
    // end-of-tile: my LDS reads are consumed (lgkm waits precede each MFMA use);
    // raw barrier (NO vmcnt drain - keeps next-tile loads in flight)
    asm volatile("s_waitcnt lgkmcnt(0)" ::: "memory");
    __builtin_amdgcn_s_barrier();
    __builtin_amdgcn_sched_barrier(0);
  }

  #pragma unroll
  for(int it=0;it<2;it++) Ls[w][it][lr][lq] = lsum[it];
  #pragma unroll
  for(int it=0;it<2;it++){
    #pragma unroll
    for(int r=0;r<4;r++){
      int n = q0 + w*32 + it*16 + lq*4 + r;
      if(n <= 576){
        int q16 = lq*4 + r;
        float lt = Ls[w][it][q16][0] + Ls[w][it][q16][1] + Ls[w][it][q16][2] + Ls[w][it][q16][3];
        float inv = 1.f / lt;
        #pragma unroll
        for(int dt=0;dt<4;dt++)
          aout[(size_t)(b*577+n)*768 + h*64 + dt*16 + lr] = f2bf(acc_o[it][dt][r]*inv);
      }
    }
  }
}

// ---------------- fp32 top-k path (exact ranking) ----------------
__global__ void k_qcls(const float* __restrict__ x, const float* __restrict__ Wqkv,
                       float* __restrict__ qcls){
  __shared__ float xs[768];
  __shared__ float part[4][64];
  const int b = blockIdx.y, j0 = blockIdx.x*64;
  const int t = threadIdx.x;
  const float* xr = x + (size_t)b*577*768;
  xs[t] = xr[t]; xs[t+256] = xr[t+256]; xs[t+512] = xr[t+512];
  __syncthreads();
  const int jl = t & 63, cs = t >> 6;
  float acc = 0.f;
  const float* wp = Wqkv + (size_t)(cs*192)*2304 + j0 + jl;
  #pragma unroll 4
  for(int c=0;c<192;c++){ acc += xs[cs*192+c] * wp[0]; wp += 2304; }
  part[cs][jl] = acc;
  __syncthreads();
  if(t < 64) qcls[b*768 + j0 + t] = part[0][t]+part[1][t]+part[2][t]+part[3][t];
}
__global__ void k_u(const float* __restrict__ Wqkv, const float* __restrict__ qcls,
                    float* __restrict__ u){
  int h = blockIdx.x, b = blockIdx.y, c = threadIdx.x;  // 768 threads
  const float* qc = qcls + b*768 + h*64;
  const float* wr = Wqkv + (size_t)c*2304 + 768 + h*64;
  float acc = 0.f;
  #pragma unroll
  for(int d=0;d<64;d++) acc += wr[d]*qc[d];
  u[(size_t)(b*12+h)*768 + c] = acc;
}
__global__ void k_attw(const float* __restrict__ x, const float* __restrict__ u,
                       float* __restrict__ attw){
  int blk = blockIdx.x;               // 16*577 blocks of 1 wave
  int b = blk/577, m = blk%577;
  int lane = threadIdx.x;
  const float* xr = x + (size_t)(b*577+m)*768;
  const float* ub = u + (size_t)b*12*768;
  float part[12];
  #pragma unroll
  for(int h=0;h<12;h++) part[h]=0.f;
  #pragma unroll
  for(int i=0;i<12;i++){
    float xv = xr[i*64 + lane];
    #pragma unroll
    for(int h=0;h<12;h++) part[h] += xv * ub[h*768 + i*64 + lane];
  }
  float s = 0.f;
  #pragma unroll
  for(int h=0;h<12;h++){
    float v = part[h];
    #pragma unroll
    for(int off=32; off; off>>=1) v += __shfl_xor(v, off);
    s += fabsf(v);
  }
  if(lane==0) attw[b*577 + m] = 0.125f * s;
}
__global__ void k_topk(const float* __restrict__ attw, int* __restrict__ idxbuf){
  __shared__ float sw[576];
  __shared__ int wtot[9];
  int b = blockIdx.x, t = threadIdx.x;     // 576 threads
  float wv = attw[b*577 + 1 + t];
  sw[t] = wv;
  __syncthreads();
  int rank = 0;
  for(int j=0;j<576;j++){
    float wj = sw[j];
    rank += (wj > wv) || (wj == wv && j < t);
  }
  bool kept = rank < NKEEP;
  unsigned long long mask = __ballot(kept);
  int wid = t>>6, lane = t&63;
  int pos = __popcll(mask & ((1ull<<lane)-1ull));
  if(lane==0) wtot[wid] = __popcll(mask);
  __syncthreads();
  int off0 = 0;
  for(int q=0;q<wid;q++) off0 += wtot[q];
  if(kept) idxbuf[b*KROWS + 1 + off0 + pos] = t+1;
  if(t==0) idxbuf[b*KROWS] = 0;
}
__global__ void k_fill_keep(const int* __restrict__ idxbuf, float* __restrict__ out2){
  int i4 = blockIdx.x*256 + threadIdx.x;
  float v = (float)idxbuf[i4/192];
  ((float4*)out2)[i4] = make_float4(v,v,v,v);
}

extern "C" void kernel_launch(void* const* d_in, const int* in_sizes, int n_in,
                              void* d_out, int out_size, void* d_ws, size_t ws_size,
                              hipStream_t stream){
  const float* x     = (const float*)d_in[0];
  const float* Wqkv  = (const float*)d_in[1];
  const float* Wproj = (const float*)d_in[2];
  const float* bias  = (const float*)d_in[3];
  float* out  = (float*)d_out;
  float* out2 = out + (size_t)M_*768;      // keep_index chunk (float32)

  char* ws = (char*)d_ws;
  size_t off = 0;
  auto alloc = [&](size_t bytes)->void*{ void* p = ws + off; off += (bytes + 255) & ~(size_t)255; return p; };
  unsigned short* xb     = (unsigned short*)alloc((size_t)M_*768*2);
  unsigned short* wqkvT  = (unsigned short*)alloc((size_t)QKVN*768*2);
  unsigned short* wprojT = (unsigned short*)alloc((size_t)768*768*2);
  unsigned short* qkvb   = (unsigned short*)alloc((size_t)M_*QKVN*2);
  unsigned short* aoutb  = (unsigned short*)alloc((size_t)M_*768*2);
  unsigned short* vtbuf  = (unsigned short*)alloc((size_t)192*64*VTLD*2);
  float* qcls   = (float*)alloc((size_t)16*768*4);
  float* u      = (float*)alloc((size_t)16*12*768*4);
  float* attw   = (float*)alloc((size_t)16*577*4);
  int*   idxbuf = (int*)alloc((size_t)16*KROWS*4);

  // bf16 casts / transposes
  k_cvt_x<<<6924, 256, 0, stream>>>(x, xb);
  k_transpose_cvt<<<dim3(36,12), 256, 0, stream>>>(Wqkv,  wqkvT, 768, 2304);
  k_transpose_cvt<<<dim3(12,12), 256, 0, stream>>>(Wproj, wprojT, 768, 768);
  // QKV GEMM (bf16 out; V-tiles written transposed into vtbuf). Frozen round-0 form.
  k_gemm_bt<QKVN, true, true, 18><<<73*18, 256, 0, stream>>>(xb, wqkvT, qkvb, nullptr, M_, vtbuf);
  // fp32 top-k weight path
  k_qcls<<<dim3(12,16), 256, 0, stream>>>(x, Wqkv, qcls);
  k_u<<<dim3(12,16), 768, 0, stream>>>(Wqkv, qcls, u);
  k_attw<<<16*577, 64, 0, stream>>>(x, u, attw);
  k_topk<<<16, 576, 0, stream>>>(attw, idxbuf);
  k_fill_keep<<<(16*KROWS*768/4 + 255)/256, 256, 0, stream>>>(idxbuf, out2);
  // attention + out-proj
  k_attn<<<960, 256, 0, stream>>>(qkvb, vtbuf, aoutb);
  k_gemm_bt64<<<145*6, 256, 0, stream>>>(aoutb, wprojT, out, bias, M_);
}

// Round 7
// 271.547 us; speedup vs baseline: 1.3567x; 1.0364x over previous
//
#include <hip/hip_runtime.h>
#include <hip/hip_bf16.h>
#include <stdint.h>

// Problem constants
#define B_    16
#define N_    577
#define C_    768
#define H_    12
#define M_    (B_*N_)     // 9232 rows
#define QKVN  (3*C_)      // 2304
#define NKEEP 403         // int(576*0.7)
#define KROWS (NKEEP+1)   // 404
#define VTLD  640         // vtbuf padded row length
#define PTLD  72          // Ptt row stride (ushorts)

typedef short s16x8 __attribute__((ext_vector_type(8)));
typedef float f32x4 __attribute__((ext_vector_type(4)));

__device__ __forceinline__ unsigned short f2bf(float x){
  unsigned int u = __float_as_uint(x);
  u += 0x7FFF + ((u >> 16) & 1);          // round-to-nearest-even
  return (unsigned short)(u >> 16);
}

// async global->LDS, 16B per lane; lds dest = wave-uniform base + lane*16
__device__ __forceinline__ void gld_lds16(const void* g, void* l){
  __builtin_amdgcn_global_load_lds(
      (const __attribute__((address_space(1))) unsigned int*)g,
      (__attribute__((address_space(3))) unsigned int*)l, 16, 0, 0);
}

// Generic XCD-panel tile mapping: xcd = L&7 owns m-panel [x*M9, x*M9+M9);
// tail m-tiles (>= 8*M9) distributed to match round-robin per-XCD counts (bijective).
template<int NT, int M9, int MTILES>
__device__ __forceinline__ void tile_map(int L, int& mt, int& nt){
  constexpr int NB = MTILES*NT;
  int x = L & 7, j = L >> 3;
  if(j < M9*NT){
    nt = j/M9; mt = x*M9 + (j - nt*M9);    // n-outer: M9 consecutive blocks share B-tile
  } else {
    int offt = 0;
    #pragma unroll
    for(int y=0;y<8;y++) if(y<x) offt += ((NB-1-y)>>3) + 1 - M9*NT;  // tail_y
    int ft = offt + (j - M9*NT);
    mt = 8*M9 + ft/NT;
    nt = ft - (ft/NT)*NT;
  }
}

// =============== fused prep: cvt_x | transpose Wqkv | transpose Wproj | qcls ===============
// Region split (r6 bug fixed): cvt [0,6924) | WqkvT [6924,7356) | WprojT [7356,7500) | qcls [7500,7692)
__global__ __launch_bounds__(256) void k_prep(const float* __restrict__ x,
                       const float* __restrict__ Wqkv, const float* __restrict__ Wproj,
                       unsigned short* __restrict__ xb, unsigned short* __restrict__ wqkvT,
                       unsigned short* __restrict__ wprojT, float* __restrict__ qcls){
  __shared__ float tile[64][65];
  __shared__ float part[4][64];
  const int bid = blockIdx.x, t = threadIdx.x;
  if(bid < 6924){
    // ---- cast x -> bf16 (vectorized); 6924*256*4 = 9232*768 elements
    int i = bid*256 + t;
    float4 v = ((const float4*)x)[i];
    ushort4 o; o.x=f2bf(v.x); o.y=f2bf(v.y); o.z=f2bf(v.z); o.w=f2bf(v.w);
    ((ushort4*)xb)[i] = o;
  } else if(bid < 7500){
    // ---- transpose+cast: Wqkv (36x12 tiles) then Wproj (12x12 tiles)
    const float* in; unsigned short* out; int R, CC, bx, by;
    if(bid < 7356){ int r = bid - 6924; bx = r % 36; by = r / 36; in = Wqkv;  out = wqkvT;  R = 768; CC = 2304; }
    else          { int r = bid - 7356; bx = r % 12; by = r / 12; in = Wproj; out = wprojT; R = 768; CC = 768;  }
    int r0 = by*64, c0 = bx*64;
    int tx = t & 63, ty = t >> 6;
    #pragma unroll
    for(int i=0;i<16;i++){
      int r = ty + i*4;
      tile[r][tx] = in[(size_t)(r0+r)*CC + c0 + tx];
    }
    __syncthreads();
    #pragma unroll
    for(int i=0;i<16;i++){
      int c = ty + i*4;
      out[(size_t)(c0+c)*R + r0 + tx] = f2bf(tile[tx][c]);
    }
  } else {
    // ---- qcls: fp32 Q row of CLS token (12 j-tiles x 16 batches)
    int r = bid - 7500;
    const int b = r / 12, j0 = (r % 12)*64;
    float* xs = &tile[0][0];                     // reuse 768 floats of tile
    const float* xr = x + (size_t)b*577*768;
    xs[t] = xr[t]; xs[t+256] = xr[t+256]; xs[t+512] = xr[t+512];
    __syncthreads();
    const int jl = t & 63, cs = t >> 6;
    float acc = 0.f;
    const float* wp = Wqkv + (size_t)(cs*192)*2304 + j0 + jl;
    #pragma unroll 4
    for(int c=0;c<192;c++){ acc += xs[cs*192+c] * wp[0]; wp += 2304; }
    part[cs][jl] = acc;
    __syncthreads();
    if(t < 64) qcls[b*768 + j0 + t] = part[0][t]+part[1][t]+part[2][t]+part[3][t];
  }
}

// ---------------- bf16 MFMA GEMM, 128x128 tile, BK=32 (r0 frozen form; used for GEMM2) ----------------
template<int LDC_, bool BF16OUT, bool FUSEV, int NT>
__global__ __launch_bounds__(256) void k_gemm_bt(const unsigned short* __restrict__ A,
                          const unsigned short* __restrict__ Bt,
                          void* __restrict__ Cout,
                          const float* __restrict__ bias, int Mdim,
                          unsigned short* __restrict__ vtbuf){
  __shared__ __align__(16) unsigned short As[128*32];
  __shared__ __align__(16) unsigned short Bs[128*32];
  const int t = threadIdx.x;
  const int w = t>>6, l = t&63, lq = l>>4, lr = l&15;
  const int wm = w>>1, wn = w&1;
  int mt, nt; tile_map<NT, 9, 73>(blockIdx.x, mt, nt);
  const int m0 = mt*128, n0 = nt*128;
  int rA0 = m0 + (t>>2);       if(rA0 >= Mdim) rA0 = Mdim-1;
  int rA1 = m0 + ((t+256)>>2); if(rA1 >= Mdim) rA1 = Mdim-1;
  const unsigned short* gA0 = A  + (size_t)rA0*768 + (t&3)*8;
  const unsigned short* gA1 = A  + (size_t)rA1*768 + (t&3)*8;
  const unsigned short* gB0 = Bt + (size_t)(n0 + (t>>2))*768 + (t&3)*8;
  const unsigned short* gB1 = Bt + (size_t)(n0 + ((t+256)>>2))*768 + (t&3)*8;
  unsigned short* lA0 = As + (size_t)w*512;
  unsigned short* lA1 = As + 2048 + (size_t)w*512;
  unsigned short* lB0 = Bs + (size_t)w*512;
  unsigned short* lB1 = Bs + 2048 + (size_t)w*512;
  f32x4 acc[4][4] = {};
  for(int kt=0; kt<24; ++kt){
    const int ko = kt*32;
    __syncthreads();
    gld_lds16(gA0 + ko, lA0); gld_lds16(gA1 + ko, lA1);
    gld_lds16(gB0 + ko, lB0); gld_lds16(gB1 + ko, lB1);
    __syncthreads();
    s16x8 af[4], bfr[4];
    #pragma unroll
    for(int it=0;it<4;it++) af[it]  = *(const s16x8*)&As[(wm*64+it*16+lr)*32 + lq*8];
    #pragma unroll
    for(int jt=0;jt<4;jt++) bfr[jt] = *(const s16x8*)&Bs[(wn*64+jt*16+lr)*32 + lq*8];
    #pragma unroll
    for(int it=0;it<4;it++)
      #pragma unroll
      for(int jt=0;jt<4;jt++)
        acc[it][jt] = __builtin_amdgcn_mfma_f32_16x16x32_bf16(af[it], bfr[jt], acc[it][jt], 0,0,0);
  }
  if(FUSEV && n0 >= 1536){
    #pragma unroll
    for(int it=0;it<4;it++){
      int tok0 = m0 + wm*64 + it*16 + lq*4;
      #pragma unroll
      for(int jt=0;jt<4;jt++){
        int vrow = (n0 - 1536) + wn*64 + jt*16 + lr;
        ushort4 pk; unsigned short* pks = (unsigned short*)&pk;
        #pragma unroll
        for(int r=0;r<4;r++) pks[r] = f2bf(acc[it][jt][r]);
        int b0 = tok0/577, t0 = tok0 - b0*577;
        if(tok0 + 3 < M_ && t0 + 3 < 577){
          *(ushort4*)&vtbuf[(size_t)(b0*768 + vrow)*VTLD + t0] = pk;
        } else {
          #pragma unroll
          for(int r=0;r<4;r++){
            int tg = tok0 + r;
            if(tg < M_){
              int bb = tg/577, tt = tg - bb*577;
              vtbuf[(size_t)(bb*768 + vrow)*VTLD + tt] = pks[r];
            }
          }
        }
      }
    }
  } else {
    #pragma unroll
    for(int it=0;it<4;it++){
      #pragma unroll
      for(int r=0;r<4;r++){
        int row = m0 + wm*64 + it*16 + lq*4 + r;
        if(row < Mdim){
          #pragma unroll
          for(int jt=0;jt<4;jt++){
            int col = n0 + wn*64 + jt*16 + lr;
            float v = acc[it][jt][r];
            if constexpr (BF16OUT)
              ((unsigned short*)Cout)[(size_t)row*LDC_ + col] = f2bf(v);
            else
              ((float*)Cout)[(size_t)row*LDC_ + col] = v + bias[col];
          }
        }
      }
    }
  }
}

// ---------------- GEMM1 (round 7 = round 6 retry): 128x128 tile, BK=64 single-buffer ----------------
// Halves the per-block drain count (24 -> 12 full vmcnt(0)+barrier cycles); 32 MFMA per
// drain. [128][64] rows would be a 16-way read conflict -> attn-proven both-sides swizzle:
// source col pre-XORed by ((t&7)^((t>>3)&7))<<3, read chunk (ks*4+lq)^(row&7) (rule #21).
// MFMA k-order identical to BK=32 form -> absmax unchanged. LDS 32 KiB.
template<int LDC_, bool BF16OUT, bool FUSEV, int NT>
__global__ __launch_bounds__(256) void k_gemm_bt_k64(const unsigned short* __restrict__ A,
                          const unsigned short* __restrict__ Bt,
                          void* __restrict__ Cout,
                          const float* __restrict__ bias, int Mdim,
                          unsigned short* __restrict__ vtbuf){
  __shared__ __align__(16) unsigned short As[128*64];   // 16 KB
  __shared__ __align__(16) unsigned short Bs[128*64];   // 16 KB
  const int t = threadIdx.x;
  const int w = t>>6, l = t&63, lq = l>>4, lr = l&15;
  const int wm = w>>1, wn = w&1;
  int mt, nt; tile_map<NT, 9, 73>(blockIdx.x, mt, nt);
  const int m0 = mt*128, n0 = nt*128;
  // staging: issue i covers rows i*32 + (t>>3); 16B chunk (t&7), source pre-swizzled
  const int srow = t>>3;                                   // 0..31
  const int csw  = (((t&7) ^ ((t>>3)&7))<<3);              // ushort col offset
  const unsigned short* gA[4]; const unsigned short* gB[4];
  #pragma unroll
  for(int i=0;i<4;i++){
    int ra = m0 + i*32 + srow; if(ra >= Mdim) ra = Mdim-1; // +32 preserves row&7
    gA[i] = A  + (size_t)ra*768 + csw;
    gB[i] = Bt + (size_t)(n0 + i*32 + srow)*768 + csw;
  }
  unsigned short* dA = As + (size_t)w*512;
  unsigned short* dB = Bs + (size_t)w*512;
  const int rxa = lr&7;                                    // row&7 for all my fragment rows
  f32x4 acc[4][4] = {};
  for(int kt=0; kt<12; ++kt){
    const int ko = kt*64;
    __syncthreads();
    #pragma unroll
    for(int i=0;i<4;i++){
      gld_lds16(gA[i] + ko, dA + i*2048);
      gld_lds16(gB[i] + ko, dB + i*2048);
    }
    __syncthreads();
    #pragma unroll
    for(int ks=0;ks<2;ks++){
      s16x8 af[4], bfr[4];
      const int cx = ((ks*4 + lq) ^ rxa) << 3;
      #pragma unroll
      for(int it=0;it<4;it++) af[it]  = *(const s16x8*)&As[(wm*64+it*16+lr)*64 + cx];
      #pragma unroll
      for(int jt=0;jt<4;jt++) bfr[jt] = *(const s16x8*)&Bs[(wn*64+jt*16+lr)*64 + cx];
      #pragma unroll
      for(int it=0;it<4;it++)
        #pragma unroll
        for(int jt=0;jt<4;jt++)
          acc[it][jt] = __builtin_amdgcn_mfma_f32_16x16x32_bf16(af[it], bfr[jt], acc[it][jt], 0,0,0);
    }
  }
  if(FUSEV && n0 >= 1536){
    #pragma unroll
    for(int it=0;it<4;it++){
      int tok0 = m0 + wm*64 + it*16 + lq*4;
      #pragma unroll
      for(int jt=0;jt<4;jt++){
        int vrow = (n0 - 1536) + wn*64 + jt*16 + lr;
        ushort4 pk; unsigned short* pks = (unsigned short*)&pk;
        #pragma unroll
        for(int r=0;r<4;r++) pks[r] = f2bf(acc[it][jt][r]);
        int b0 = tok0/577, t0 = tok0 - b0*577;
        if(tok0 + 3 < M_ && t0 + 3 < 577){
          *(ushort4*)&vtbuf[(size_t)(b0*768 + vrow)*VTLD + t0] = pk;
        } else {
          #pragma unroll
          for(int r=0;r<4;r++){
            int tg = tok0 + r;
            if(tg < M_){
              int bb = tg/577, tt = tg - bb*577;
              vtbuf[(size_t)(bb*768 + vrow)*VTLD + tt] = pks[r];
            }
          }
        }
      }
    }
  } else {
    #pragma unroll
    for(int it=0;it<4;it++){
      #pragma unroll
      for(int r=0;r<4;r++){
        int row = m0 + wm*64 + it*16 + lq*4 + r;
        if(row < Mdim){
          #pragma unroll
          for(int jt=0;jt<4;jt++){
            int col = n0 + wn*64 + jt*16 + lr;
            float v = acc[it][jt][r];
            if constexpr (BF16OUT)
              ((unsigned short*)Cout)[(size_t)row*LDC_ + col] = f2bf(v);
            else
              ((float*)Cout)[(size_t)row*LDC_ + col] = v + bias[col];
          }
        }
      }
    }
  }
}

// ---------------- fused flash attention (r5 T14 form, kept) ----------------
__global__ __launch_bounds__(256,4) void k_attn(const unsigned short* __restrict__ qkv,
                                                const unsigned short* __restrict__ vtbuf,
                                                unsigned short* __restrict__ aout){
  __shared__ __align__(16) unsigned short Ks[64*64];
  __shared__ __align__(16) unsigned short Vt[64*64];
  __shared__ __align__(16) unsigned short Ptt[128*PTLD];
  __shared__ float Ls[4][2][16][4];
  const int blk = blockIdx.x;
  const int bh = blk % 192, qt = blk / 192;
  const int b = bh / 12, h = bh % 12;
  const int t = threadIdx.x, w = t>>6, l = t&63, lq = l>>4, lr = l&15;
  const size_t base = (size_t)(b*577)*2304 + h*64;
  const int q0 = qt*128;
  s16x8 bq[2][2];
  #pragma unroll
  for(int it=0;it<2;it++){
    int qrow = q0 + w*32 + it*16 + lr; if(qrow > 576) qrow = 576;
    #pragma unroll
    for(int ks=0;ks<2;ks++)
      bq[it][ks] = *(const s16x8*)&qkv[base + (size_t)qrow*2304 + ks*32 + lq*8];
  }
  const int srow = w*8 + (l>>3);
  const int cswz8 = (((l&7) ^ (l>>3)) << 3);
  unsigned short* ldsK = Ks + w*512 + l*8;
  unsigned short* ldsV = Vt + w*512 + l*8;
  const unsigned short* gVbase = vtbuf + (size_t)(bh*64)*VTLD + cswz8;

  f32x4 acc_o[2][4] = {};
  float lsum[2] = {0.f, 0.f};
  const float CEXP = 0.18033688011112043f;              // 0.125 * log2(e)

  s16x8 kreg0, kreg1, vreg0, vreg1;
  auto stage_issue = [&](int tt){
    const int j0i = tt*64;
    int kr0 = j0i + srow;      if(kr0 > 576) kr0 = 576;
    int kr1 = j0i + 32 + srow; if(kr1 > 576) kr1 = 576;
    kreg0 = *(const s16x8*)(qkv + base + 768 + (size_t)kr0*2304 + cswz8);
    kreg1 = *(const s16x8*)(qkv + base + 768 + (size_t)kr1*2304 + cswz8);
    vreg0 = *(const s16x8*)(gVbase + (size_t)srow*VTLD + j0i);
    vreg1 = *(const s16x8*)(gVbase + (size_t)(32 + srow)*VTLD + j0i);
  };

  stage_issue(0);
  for(int g=0; g<10; ++g){
    const int j0 = g*64;
    const bool edge = (g == 9);
    *(s16x8*)(ldsK)        = kreg0;
    *(s16x8*)(ldsK + 2048) = kreg1;
    *(s16x8*)(ldsV)        = vreg0;
    *(s16x8*)(ldsV + 2048) = vreg1;
    asm volatile("s_waitcnt lgkmcnt(0)" ::: "memory");
    __builtin_amdgcn_s_barrier();
    __builtin_amdgcn_sched_barrier(0);
    if(g < 9) stage_issue(g+1);

    f32x4 accs[2][4] = {};
    #pragma unroll
    for(int ks=0;ks<2;ks++){
      s16x8 ak[4];
      #pragma unroll
      for(int jt=0;jt<4;jt++){
        int j = jt*16 + lr;
        ak[jt] = *(const s16x8*)&Ks[j*64 + (((4*ks+lq) ^ (j&7))<<3)];
      }
      #pragma unroll
      for(int it=0;it<2;it++)
        #pragma unroll
        for(int jt=0;jt<4;jt++)
          accs[it][jt] = __builtin_amdgcn_mfma_f32_16x16x32_bf16(ak[jt], bq[it][ks], accs[it][jt], 0,0,0);
    }
    #pragma unroll
    for(int it=0;it<2;it++){
      int qlocal = w*32 + it*16 + lr;
      #pragma unroll
      for(int jt=0;jt<4;jt++){
        ushort4 pk;
        unsigned short* pks = (unsigned short*)&pk;
        #pragma unroll
        for(int r=0;r<4;r++){
          float p = exp2f(accs[it][jt][r] * CEXP);
          if(edge){ if(j0 + jt*16 + lq*4 + r > 576) p = 0.f; }
          lsum[it] += p;
          pks[r] = f2bf(p);
        }
        *(ushort4*)&Ptt[qlocal*PTLD + jt*16 + lq*4] = pk;
      }
    }
    #pragma unroll
    for(int ks=0;ks<2;ks++){
      s16x8 ap[2], bv[4];
      #pragma unroll
      for(int it=0;it<2;it++)
        ap[it] = *(const s16x8*)&Ptt[(w*32+it*16+lr)*PTLD + ks*32 + lq*8];
      #pragma unroll
      for(int dt=0;dt<4;dt++){
        int d = dt*16 + lr;
        bv[dt] = *(const s16x8*)&Vt[d*64 + (((4*ks+lq) ^ (d&7))<<3)];
      }
      #pragma unroll
      for(int it=0;it<2;it++)
        #pragma unroll
        for(int dt=0;dt<4;dt++)
          acc_o[it][dt] = __builtin_amdgcn_mfma_f32_16x16x32_bf16(ap[it], bv[dt], acc_o[it][dt], 0,0,0);
    }
    asm volatile("s_waitcnt lgkmcnt(0)" ::: "memory");
    __builtin_amdgcn_s_barrier();
    __builtin_amdgcn_sched_barrier(0);
  }

  #pragma unroll
  for(int it=0;it<2;it++) Ls[w][it][lr][lq] = lsum[it];
  #pragma unroll
  for(int it=0;it<2;it++){
    #pragma unroll
    for(int r=0;r<4;r++){
      int n = q0 + w*32 + it*16 + lq*4 + r;
      if(n <= 576){
        int q16 = lq*4 + r;
        float lt = Ls[w][it][q16][0] + Ls[w][it][q16][1] + Ls[w][it][q16][2] + Ls[w][it][q16][3];
        float inv = 1.f / lt;
        #pragma unroll
        for(int dt=0;dt<4;dt++)
          aout[(size_t)(b*577+n)*768 + h*64 + dt*16 + lr] = f2bf(acc_o[it][dt][r]*inv);
      }
    }
  }
}

// ---------------- fp32 top-k path ----------------
__global__ void k_u(const float* __restrict__ Wqkv, const float* __restrict__ qcls,
                    float* __restrict__ u){
  int h = blockIdx.x, b = blockIdx.y, c = threadIdx.x;  // 768 threads
  const float* qc = qcls + b*768 + h*64;
  const float* wr = Wqkv + (size_t)c*2304 + 768 + h*64;
  float acc = 0.f;
  #pragma unroll
  for(int d=0;d<64;d++) acc += wr[d]*qc[d];
  u[(size_t)(b*12+h)*768 + c] = acc;
}
__global__ void k_attw(const float* __restrict__ x, const float* __restrict__ u,
                       float* __restrict__ attw){
  int blk = blockIdx.x;               // 16*577 blocks of 1 wave
  int b = blk/577, m = blk%577;
  int lane = threadIdx.x;
  const float* xr = x + (size_t)(b*577+m)*768;
  const float* ub = u + (size_t)b*12*768;
  float part[12];
  #pragma unroll
  for(int h=0;h<12;h++) part[h]=0.f;
  #pragma unroll
  for(int i=0;i<12;i++){
    float xv = xr[i*64 + lane];
    #pragma unroll
    for(int h=0;h<12;h++) part[h] += xv * ub[h*768 + i*64 + lane];
  }
  float s = 0.f;
  #pragma unroll
  for(int h=0;h<12;h++){
    float v = part[h];
    #pragma unroll
    for(int off=32; off; off>>=1) v += __shfl_xor(v, off);
    s += fabsf(v);
  }
  if(lane==0) attw[b*577 + m] = 0.125f * s;
}
// ---- fused top-k + keep_index broadcast write (saves a launch + idxbuf round-trip)
__global__ void k_topk_fill(const float* __restrict__ attw, float* __restrict__ out2){
  __shared__ float sw[576];
  __shared__ int wtot[9];
  __shared__ int sidx[KROWS];
  int b = blockIdx.x, t = threadIdx.x;     // 576 threads
  float wv = attw[b*577 + 1 + t];
  sw[t] = wv;
  __syncthreads();
  int rank = 0;
  for(int j=0;j<576;j++){
    float wj = sw[j];
    rank += (wj > wv) || (wj == wv && j < t);
  }
  bool kept = rank < NKEEP;
  unsigned long long mask = __ballot(kept);
  int wid = t>>6, lane = t&63;
  int pos = __popcll(mask & ((1ull<<lane)-1ull));
  if(lane==0) wtot[wid] = __popcll(mask);
  __syncthreads();
  int off0 = 0;
  for(int q=0;q<wid;q++) off0 += wtot[q];
  if(kept) sidx[1 + off0 + pos] = t+1;
  if(t==0) sidx[0] = 0;
  __syncthreads();
  // broadcast write: out2[b][row][0..767] = (float)sidx[row], 192 float4 per row
  float4* o4 = (float4*)out2 + (size_t)b*KROWS*192;
  for(int i = t; i < KROWS*192; i += 576){
    float v = (float)sidx[i/192];
    o4[i] = make_float4(v,v,v,v);
  }
}

extern "C" void kernel_launch(void* const* d_in, const int* in_sizes, int n_in,
                              void* d_out, int out_size, void* d_ws, size_t ws_size,
                              hipStream_t stream){
  const float* x     = (const float*)d_in[0];
  const float* Wqkv  = (const float*)d_in[1];
  const float* Wproj = (const float*)d_in[2];
  const float* bias  = (const float*)d_in[3];
  float* out  = (float*)d_out;
  float* out2 = out + (size_t)M_*768;      // keep_index chunk (float32)

  char* ws = (char*)d_ws;
  size_t off = 0;
  auto alloc = [&](size_t bytes)->void*{ void* p = ws + off; off += (bytes + 255) & ~(size_t)255; return p; };
  unsigned short* xb     = (unsigned short*)alloc((size_t)M_*768*2);
  unsigned short* wqkvT  = (unsigned short*)alloc((size_t)QKVN*768*2);
  unsigned short* wprojT = (unsigned short*)alloc((size_t)768*768*2);
  unsigned short* qkvb   = (unsigned short*)alloc((size_t)M_*QKVN*2);
  unsigned short* aoutb  = (unsigned short*)alloc((size_t)M_*768*2);
  unsigned short* vtbuf  = (unsigned short*)alloc((size_t)192*64*VTLD*2);
  float* qcls   = (float*)alloc((size_t)16*768*4);
  float* u      = (float*)alloc((size_t)16*12*768*4);
  float* attw   = (float*)alloc((size_t)16*577*4);

  // fused prep: cvt_x | transpose Wqkv | transpose Wproj | qcls  (7692 blocks)
  k_prep<<<7692, 256, 0, stream>>>(x, Wqkv, Wproj, xb, wqkvT, wprojT, qcls);
  // QKV GEMM (bf16 out; V-tiles written transposed into vtbuf). BK=64 single-buffer.
  k_gemm_bt_k64<QKVN, true, true, 18><<<73*18, 256, 0, stream>>>(xb, wqkvT, qkvb, nullptr, M_, vtbuf);
  // fp32 top-k weight path
  k_u<<<dim3(12,16), 768, 0, stream>>>(Wqkv, qcls, u);
  k_attw<<<16*577, 64, 0, stream>>>(x, u, attw);
  k_topk_fill<<<16, 576, 0, stream>>>(attw, out2);
  // attention + out-proj (128^2 template, 438 blocks)
  k_attn<<<960, 256, 0, stream>>>(qkvb, vtbuf, aoutb);
  k_gemm_bt<768, false, false, 6><<<73*6, 256, 0, stream>>>(aoutb, wprojT, out, bias, M_, nullptr);
}

// Round 8
// 264.927 us; speedup vs baseline: 1.3906x; 1.0250x over previous
//
#include <hip/hip_runtime.h>
#include <hip/hip_bf16.h>
#include <stdint.h>

// Problem constants
#define B_    16
#define N_    577
#define C_    768
#define H_    12
#define M_    (B_*N_)     // 9232 rows
#define QKVN  (3*C_)      // 2304
#define NKEEP 403         // int(576*0.7)
#define KROWS (NKEEP+1)   // 404
#define VTLD  640         // vtbuf padded row length
#define PTLD  72          // Ptt row stride (ushorts)

typedef short s16x8 __attribute__((ext_vector_type(8)));
typedef float f32x4 __attribute__((ext_vector_type(4)));

__device__ __forceinline__ unsigned short f2bf(float x){
  unsigned int u = __float_as_uint(x);
  u += 0x7FFF + ((u >> 16) & 1);          // round-to-nearest-even
  return (unsigned short)(u >> 16);
}

// async global->LDS, 16B per lane; lds dest = wave-uniform base + lane*16
__device__ __forceinline__ void gld_lds16(const void* g, void* l){
  __builtin_amdgcn_global_load_lds(
      (const __attribute__((address_space(1))) unsigned int*)g,
      (__attribute__((address_space(3))) unsigned int*)l, 16, 0, 0);
}

// Generic XCD-panel tile mapping: xcd = L&7 owns m-panel [x*M9, x*M9+M9);
// tail m-tiles (>= 8*M9) distributed to match round-robin per-XCD counts (bijective).
template<int NT, int M9, int MTILES>
__device__ __forceinline__ void tile_map(int L, int& mt, int& nt){
  constexpr int NB = MTILES*NT;
  int x = L & 7, j = L >> 3;
  if(j < M9*NT){
    nt = j/M9; mt = x*M9 + (j - nt*M9);    // n-outer: M9 consecutive blocks share B-tile
  } else {
    int offt = 0;
    #pragma unroll
    for(int y=0;y<8;y++) if(y<x) offt += ((NB-1-y)>>3) + 1 - M9*NT;  // tail_y
    int ft = offt + (j - M9*NT);
    mt = 8*M9 + ft/NT;
    nt = ft - (ft/NT)*NT;
  }
}

// =============== fused prep: cvt_x | transpose Wqkv | transpose Wproj | qcls ===============
// Region split: cvt [0,6924) | WqkvT [6924,7356) | WprojT [7356,7500) | qcls [7500,7692)
__global__ __launch_bounds__(256) void k_prep(const float* __restrict__ x,
                       const float* __restrict__ Wqkv, const float* __restrict__ Wproj,
                       unsigned short* __restrict__ xb, unsigned short* __restrict__ wqkvT,
                       unsigned short* __restrict__ wprojT, float* __restrict__ qcls){
  __shared__ float tile[64][65];
  __shared__ float part[4][64];
  const int bid = blockIdx.x, t = threadIdx.x;
  if(bid < 6924){
    int i = bid*256 + t;
    float4 v = ((const float4*)x)[i];
    ushort4 o; o.x=f2bf(v.x); o.y=f2bf(v.y); o.z=f2bf(v.z); o.w=f2bf(v.w);
    ((ushort4*)xb)[i] = o;
  } else if(bid < 7500){
    const float* in; unsigned short* out; int R, CC, bx, by;
    if(bid < 7356){ int r = bid - 6924; bx = r % 36; by = r / 36; in = Wqkv;  out = wqkvT;  R = 768; CC = 2304; }
    else          { int r = bid - 7356; bx = r % 12; by = r / 12; in = Wproj; out = wprojT; R = 768; CC = 768;  }
    int r0 = by*64, c0 = bx*64;
    int tx = t & 63, ty = t >> 6;
    #pragma unroll
    for(int i=0;i<16;i++){
      int r = ty + i*4;
      tile[r][tx] = in[(size_t)(r0+r)*CC + c0 + tx];
    }
    __syncthreads();
    #pragma unroll
    for(int i=0;i<16;i++){
      int c = ty + i*4;
      out[(size_t)(c0+c)*R + r0 + tx] = f2bf(tile[tx][c]);
    }
  } else {
    int r = bid - 7500;
    const int b = r / 12, j0 = (r % 12)*64;
    float* xs = &tile[0][0];
    const float* xr = x + (size_t)b*577*768;
    xs[t] = xr[t]; xs[t+256] = xr[t+256]; xs[t+512] = xr[t+512];
    __syncthreads();
    const int jl = t & 63, cs = t >> 6;
    float acc = 0.f;
    const float* wp = Wqkv + (size_t)(cs*192)*2304 + j0 + jl;
    #pragma unroll 4
    for(int c=0;c<192;c++){ acc += xs[cs*192+c] * wp[0]; wp += 2304; }
    part[cs][jl] = acc;
    __syncthreads();
    if(t < 64) qcls[b*768 + j0 + t] = part[0][t]+part[1][t]+part[2][t]+part[3][t];
  }
}

// ---------------- GEMM epilogue (shared): FUSEV V-transpose or plain C write ----------------
template<int LDC_, bool BF16OUT, bool FUSEV>
__device__ __forceinline__ void gemm_epilogue(f32x4 (&acc)[4][4], int m0, int n0,
                          int wm, int wn, int lq, int lr, void* Cout,
                          const float* bias, int Mdim, unsigned short* vtbuf){
  if(FUSEV && n0 >= 1536){
    #pragma unroll
    for(int it=0;it<4;it++){
      int tok0 = m0 + wm*64 + it*16 + lq*4;
      #pragma unroll
      for(int jt=0;jt<4;jt++){
        int vrow = (n0 - 1536) + wn*64 + jt*16 + lr;
        ushort4 pk; unsigned short* pks = (unsigned short*)&pk;
        #pragma unroll
        for(int r=0;r<4;r++) pks[r] = f2bf(acc[it][jt][r]);
        int b0 = tok0/577, t0 = tok0 - b0*577;
        if(tok0 + 3 < M_ && t0 + 3 < 577){
          *(ushort4*)&vtbuf[(size_t)(b0*768 + vrow)*VTLD + t0] = pk;
        } else {
          #pragma unroll
          for(int r=0;r<4;r++){
            int tg = tok0 + r;
            if(tg < M_){
              int bb = tg/577, tt = tg - bb*577;
              vtbuf[(size_t)(bb*768 + vrow)*VTLD + tt] = pks[r];
            }
          }
        }
      }
    }
  } else {
    #pragma unroll
    for(int it=0;it<4;it++){
      #pragma unroll
      for(int r=0;r<4;r++){
        int row = m0 + wm*64 + it*16 + lq*4 + r;
        if(row < Mdim){
          #pragma unroll
          for(int jt=0;jt<4;jt++){
            int col = n0 + wn*64 + jt*16 + lr;
            float v = acc[it][jt][r];
            if constexpr (BF16OUT)
              ((unsigned short*)Cout)[(size_t)row*LDC_ + col] = f2bf(v);
            else
              ((float*)Cout)[(size_t)row*LDC_ + col] = v + bias[col];
          }
        }
      }
    }
  }
}

// ---------------- GEMM, 128x128 tile, BK=64 single-buffer (r7 proven: 54.5us, 0 conflicts) ----------------
// Used for GEMM2. Swizzle: source col pre-XORed ((t&7)^((t>>3)&7))<<3; read chunk (ks*4+lq)^(row&7).
template<int LDC_, bool BF16OUT, bool FUSEV, int NT>
__global__ __launch_bounds__(256) void k_gemm_bt_k64(const unsigned short* __restrict__ A,
                          const unsigned short* __restrict__ Bt,
                          void* __restrict__ Cout,
                          const float* __restrict__ bias, int Mdim,
                          unsigned short* __restrict__ vtbuf){
  __shared__ __align__(16) unsigned short As[128*64];   // 16 KB
  __shared__ __align__(16) unsigned short Bs[128*64];   // 16 KB
  const int t = threadIdx.x;
  const int w = t>>6, l = t&63, lq = l>>4, lr = l&15;
  const int wm = w>>1, wn = w&1;
  int mt, nt; tile_map<NT, 9, 73>(blockIdx.x, mt, nt);
  const int m0 = mt*128, n0 = nt*128;
  const int srow = t>>3;                                   // 0..31
  const int csw  = (((t&7) ^ ((t>>3)&7))<<3);              // ushort col offset
  const unsigned short* gA[4]; const unsigned short* gB[4];
  #pragma unroll
  for(int i=0;i<4;i++){
    int ra = m0 + i*32 + srow; if(ra >= Mdim) ra = Mdim-1; // +32 preserves row&7
    gA[i] = A  + (size_t)ra*768 + csw;
    gB[i] = Bt + (size_t)(n0 + i*32 + srow)*768 + csw;
  }
  unsigned short* dA = As + (size_t)w*512;
  unsigned short* dB = Bs + (size_t)w*512;
  const int rxa = lr&7;
  f32x4 acc[4][4] = {};
  for(int kt=0; kt<12; ++kt){
    const int ko = kt*64;
    __syncthreads();
    #pragma unroll
    for(int i=0;i<4;i++){
      gld_lds16(gA[i] + ko, dA + i*2048);
      gld_lds16(gB[i] + ko, dB + i*2048);
    }
    __syncthreads();
    #pragma unroll
    for(int ks=0;ks<2;ks++){
      s16x8 af[4], bfr[4];
      const int cx = ((ks*4 + lq) ^ rxa) << 3;
      #pragma unroll
      for(int it=0;it<4;it++) af[it]  = *(const s16x8*)&As[(wm*64+it*16+lr)*64 + cx];
      #pragma unroll
      for(int jt=0;jt<4;jt++) bfr[jt] = *(const s16x8*)&Bs[(wn*64+jt*16+lr)*64 + cx];
      #pragma unroll
      for(int it=0;it<4;it++)
        #pragma unroll
        for(int jt=0;jt<4;jt++)
          acc[it][jt] = __builtin_amdgcn_mfma_f32_16x16x32_bf16(af[it], bfr[jt], acc[it][jt], 0,0,0);
    }
  }
  gemm_epilogue<LDC_, BF16OUT, FUSEV>(acc, m0, n0, wm, wn, lq, lr, Cout, bias, Mdim, vtbuf);
}

// ---------------- GEMM1 (round 8): BK=64 DOUBLE-buffer, counted vmcnt ----------------
// r7 post-mortem: single-buffer exposes a full vmcnt(0) drain per k-tile (12x). Here
// tile kt+1's loads are issued one full iteration early (covered by 16 ds_read + 32
// MFMA); the wait is vmcnt(8) AFTER the MFMA block, never a 0-drain mid-loop. Uses the
// r7 swizzle (measured 0 conflicts); accumulation order identical -> absmax unchanged.
// LDS 64 KiB -> 2 blocks/CU. Schedule per kt (slot s=kt&1):
//   READ 16 ds_read (slot s); lgkmcnt(0)+sched_barrier; barrier [all done reading s];
//   STAGE(kt+2 -> s); setprio MFMA x32; vmcnt(8) [= tile kt+1 complete]; barrier.
template<int LDC_, bool BF16OUT, bool FUSEV, int NT>
__global__ __launch_bounds__(256) void k_gemm_db(const unsigned short* __restrict__ A,
                          const unsigned short* __restrict__ Bt,
                          void* __restrict__ Cout,
                          const float* __restrict__ bias, int Mdim,
                          unsigned short* __restrict__ vtbuf){
  __shared__ __align__(16) unsigned short As[2][128*64];  // 32 KB
  __shared__ __align__(16) unsigned short Bs[2][128*64];  // 32 KB
  const int t = threadIdx.x;
  const int w = t>>6, l = t&63, lq = l>>4, lr = l&15;
  const int wm = w>>1, wn = w&1;
  int mt, nt; tile_map<NT, 9, 73>(blockIdx.x, mt, nt);
  const int m0 = mt*128, n0 = nt*128;
  const int srow = t>>3;
  const int csw  = (((t&7) ^ ((t>>3)&7))<<3);
  const unsigned short* gA[4]; const unsigned short* gB[4];
  #pragma unroll
  for(int i=0;i<4;i++){
    int ra = m0 + i*32 + srow; if(ra >= Mdim) ra = Mdim-1;
    gA[i] = A  + (size_t)ra*768 + csw;
    gB[i] = Bt + (size_t)(n0 + i*32 + srow)*768 + csw;
  }
  const int rxa = lr&7;
  f32x4 acc[4][4] = {};

#define STAGE_DB(KT, S) do{ \
  unsigned short* dA_ = &As[(S)][w*512]; \
  unsigned short* dB_ = &Bs[(S)][w*512]; \
  _Pragma("unroll") \
  for(int i_=0;i_<4;i_++){ \
    gld_lds16(gA[i_] + (size_t)(KT)*64, dA_ + i_*2048); \
    gld_lds16(gB[i_] + (size_t)(KT)*64, dB_ + i_*2048); \
  } \
}while(0)

  // prologue: tiles 0,1 in flight; wait tile 0 (oldest 8 of 16)
  STAGE_DB(0,0);
  STAGE_DB(1,1);
  asm volatile("s_waitcnt vmcnt(8)" ::: "memory");
  __builtin_amdgcn_s_barrier();

  for(int kt=0; kt<12; ++kt){
    const int s = kt&1;
    s16x8 af[4][2], bfr[4][2];
    #pragma unroll
    for(int ks=0;ks<2;ks++){
      const int cx = ((ks*4 + lq) ^ rxa) << 3;
      #pragma unroll
      for(int it=0;it<4;it++) af[it][ks]  = *(const s16x8*)&As[s][(wm*64+it*16+lr)*64 + cx];
      #pragma unroll
      for(int jt=0;jt<4;jt++) bfr[jt][ks] = *(const s16x8*)&Bs[s][(wn*64+jt*16+lr)*64 + cx];
    }
    asm volatile("s_waitcnt lgkmcnt(0)" ::: "memory");   // my reads of slot s done
    __builtin_amdgcn_sched_barrier(0);                   // rule #18: pin MFMA below
    __builtin_amdgcn_s_barrier();                        // ALL waves done reading slot s
    if(kt<10) STAGE_DB(kt+2, s);                         // overwrite freed slot
    __builtin_amdgcn_s_setprio(1);
    #pragma unroll
    for(int ks=0;ks<2;ks++)
      #pragma unroll
      for(int it=0;it<4;it++)
        #pragma unroll
        for(int jt=0;jt<4;jt++)
          acc[it][jt] = __builtin_amdgcn_mfma_f32_16x16x32_bf16(af[it][ks], bfr[jt][ks], acc[it][jt], 0,0,0);
    __builtin_amdgcn_s_setprio(0);
    if(kt<10){
      asm volatile("s_waitcnt vmcnt(8)" ::: "memory");   // tile kt+1 fully landed (mine)
    } else if(kt==10){
      asm volatile("s_waitcnt vmcnt(0)" ::: "memory");   // drain tile 11
    }
    __builtin_amdgcn_s_barrier();                        // ...and everyone else's
  }
  gemm_epilogue<LDC_, BF16OUT, FUSEV>(acc, m0, n0, wm, wn, lq, lr, Cout, bias, Mdim, vtbuf);
#undef STAGE_DB
}

// ---------------- fused flash attention (r5 T14 form, kept) ----------------
__global__ __launch_bounds__(256,4) void k_attn(const unsigned short* __restrict__ qkv,
                                                const unsigned short* __restrict__ vtbuf,
                                                unsigned short* __restrict__ aout){
  __shared__ __align__(16) unsigned short Ks[64*64];
  __shared__ __align__(16) unsigned short Vt[64*64];
  __shared__ __align__(16) unsigned short Ptt[128*PTLD];
  __shared__ float Ls[4][2][16][4];
  const int blk = blockIdx.x;
  const int bh = blk % 192, qt = blk / 192;
  const int b = bh / 12, h = bh % 12;
  const int t = threadIdx.x, w = t>>6, l = t&63, lq = l>>4, lr = l&15;
  const size_t base = (size_t)(b*577)*2304 + h*64;
  const int q0 = qt*128;
  s16x8 bq[2][2];
  #pragma unroll
  for(int it=0;it<2;it++){
    int qrow = q0 + w*32 + it*16 + lr; if(qrow > 576) qrow = 576;
    #pragma unroll
    for(int ks=0;ks<2;ks++)
      bq[it][ks] = *(const s16x8*)&qkv[base + (size_t)qrow*2304 + ks*32 + lq*8];
  }
  const int srow = w*8 + (l>>3);
  const int cswz8 = (((l&7) ^ (l>>3)) << 3);
  unsigned short* ldsK = Ks + w*512 + l*8;
  unsigned short* ldsV = Vt + w*512 + l*8;
  const unsigned short* gVbase = vtbuf + (size_t)(bh*64)*VTLD + cswz8;

  f32x4 acc_o[2][4] = {};
  float lsum[2] = {0.f, 0.f};
  const float CEXP = 0.18033688011112043f;              // 0.125 * log2(e)

  s16x8 kreg0, kreg1, vreg0, vreg1;
  auto stage_issue = [&](int tt){
    const int j0i = tt*64;
    int kr0 = j0i + srow;      if(kr0 > 576) kr0 = 576;
    int kr1 = j0i + 32 + srow; if(kr1 > 576) kr1 = 576;
    kreg0 = *(const s16x8*)(qkv + base + 768 + (size_t)kr0*2304 + cswz8);
    kreg1 = *(const s16x8*)(qkv + base + 768 + (size_t)kr1*2304 + cswz8);
    vreg0 = *(const s16x8*)(gVbase + (size_t)srow*VTLD + j0i);
    vreg1 = *(const s16x8*)(gVbase + (size_t)(32 + srow)*VTLD + j0i);
  };

  stage_issue(0);
  for(int g=0; g<10; ++g){
    const int j0 = g*64;
    const bool edge = (g == 9);
    *(s16x8*)(ldsK)        = kreg0;
    *(s16x8*)(ldsK + 2048) = kreg1;
    *(s16x8*)(ldsV)        = vreg0;
    *(s16x8*)(ldsV + 2048) = vreg1;
    asm volatile("s_waitcnt lgkmcnt(0)" ::: "memory");
    __builtin_amdgcn_s_barrier();
    __builtin_amdgcn_sched_barrier(0);
    if(g < 9) stage_issue(g+1);

    f32x4 accs[2][4] = {};
    #pragma unroll
    for(int ks=0;ks<2;ks++){
      s16x8 ak[4];
      #pragma unroll
      for(int jt=0;jt<4;jt++){
        int j = jt*16 + lr;
        ak[jt] = *(const s16x8*)&Ks[j*64 + (((4*ks+lq) ^ (j&7))<<3)];
      }
      #pragma unroll
      for(int it=0;it<2;it++)
        #pragma unroll
        for(int jt=0;jt<4;jt++)
          accs[it][jt] = __builtin_amdgcn_mfma_f32_16x16x32_bf16(ak[jt], bq[it][ks], accs[it][jt], 0,0,0);
    }
    #pragma unroll
    for(int it=0;it<2;it++){
      int qlocal = w*32 + it*16 + lr;
      #pragma unroll
      for(int jt=0;jt<4;jt++){
        ushort4 pk;
        unsigned short* pks = (unsigned short*)&pk;
        #pragma unroll
        for(int r=0;r<4;r++){
          float p = exp2f(accs[it][jt][r] * CEXP);
          if(edge){ if(j0 + jt*16 + lq*4 + r > 576) p = 0.f; }
          lsum[it] += p;
          pks[r] = f2bf(p);
        }
        *(ushort4*)&Ptt[qlocal*PTLD + jt*16 + lq*4] = pk;
      }
    }
    #pragma unroll
    for(int ks=0;ks<2;ks++){
      s16x8 ap[2], bv[4];
      #pragma unroll
      for(int it=0;it<2;it++)
        ap[it] = *(const s16x8*)&Ptt[(w*32+it*16+lr)*PTLD + ks*32 + lq*8];
      #pragma unroll
      for(int dt=0;dt<4;dt++){
        int d = dt*16 + lr;
        bv[dt] = *(const s16x8*)&Vt[d*64 + (((4*ks+lq) ^ (d&7))<<3)];
      }
      #pragma unroll
      for(int it=0;it<2;it++)
        #pragma unroll
        for(int dt=0;dt<4;dt++)
          acc_o[it][dt] = __builtin_amdgcn_mfma_f32_16x16x32_bf16(ap[it], bv[dt], acc_o[it][dt], 0,0,0);
    }
    asm volatile("s_waitcnt lgkmcnt(0)" ::: "memory");
    __builtin_amdgcn_s_barrier();
    __builtin_amdgcn_sched_barrier(0);
  }

  #pragma unroll
  for(int it=0;it<2;it++) Ls[w][it][lr][lq] = lsum[it];
  #pragma unroll
  for(int it=0;it<2;it++){
    #pragma unroll
    for(int r=0;r<4;r++){
      int n = q0 + w*32 + it*16 + lq*4 + r;
      if(n <= 576){
        int q16 = lq*4 + r;
        float lt = Ls[w][it][q16][0] + Ls[w][it][q16][1] + Ls[w][it][q16][2] + Ls[w][it][q16][3];
        float inv = 1.f / lt;
        #pragma unroll
        for(int dt=0;dt<4;dt++)
          aout[(size_t)(b*577+n)*768 + h*64 + dt*16 + lr] = f2bf(acc_o[it][dt][r]*inv);
      }
    }
  }
}

// ---------------- fp32 top-k path ----------------
__global__ void k_u(const float* __restrict__ Wqkv, const float* __restrict__ qcls,
                    float* __restrict__ u){
  int h = blockIdx.x, b = blockIdx.y, c = threadIdx.x;  // 768 threads
  const float* qc = qcls + b*768 + h*64;
  const float* wr = Wqkv + (size_t)c*2304 + 768 + h*64;
  float acc = 0.f;
  #pragma unroll
  for(int d=0;d<64;d++) acc += wr[d]*qc[d];
  u[(size_t)(b*12+h)*768 + c] = acc;
}
__global__ void k_attw(const float* __restrict__ x, const float* __restrict__ u,
                       float* __restrict__ attw){
  int blk = blockIdx.x;               // 16*577 blocks of 1 wave
  int b = blk/577, m = blk%577;
  int lane = threadIdx.x;
  const float* xr = x + (size_t)(b*577+m)*768;
  const float* ub = u + (size_t)b*12*768;
  float part[12];
  #pragma unroll
  for(int h=0;h<12;h++) part[h]=0.f;
  #pragma unroll
  for(int i=0;i<12;i++){
    float xv = xr[i*64 + lane];
    #pragma unroll
    for(int h=0;h<12;h++) part[h] += xv * ub[h*768 + i*64 + lane];
  }
  float s = 0.f;
  #pragma unroll
  for(int h=0;h<12;h++){
    float v = part[h];
    #pragma unroll
    for(int off=32; off; off>>=1) v += __shfl_xor(v, off);
    s += fabsf(v);
  }
  if(lane==0) attw[b*577 + m] = 0.125f * s;
}
// ---- fused top-k + keep_index broadcast write
__global__ void k_topk_fill(const float* __restrict__ attw, float* __restrict__ out2){
  __shared__ float sw[576];
  __shared__ int wtot[9];
  __shared__ int sidx[KROWS];
  int b = blockIdx.x, t = threadIdx.x;     // 576 threads
  float wv = attw[b*577 + 1 + t];
  sw[t] = wv;
  __syncthreads();
  int rank = 0;
  for(int j=0;j<576;j++){
    float wj = sw[j];
    rank += (wj > wv) || (wj == wv && j < t);
  }
  bool kept = rank < NKEEP;
  unsigned long long mask = __ballot(kept);
  int wid = t>>6, lane = t&63;
  int pos = __popcll(mask & ((1ull<<lane)-1ull));
  if(lane==0) wtot[wid] = __popcll(mask);
  __syncthreads();
  int off0 = 0;
  for(int q=0;q<wid;q++) off0 += wtot[q];
  if(kept) sidx[1 + off0 + pos] = t+1;
  if(t==0) sidx[0] = 0;
  __syncthreads();
  float4* o4 = (float4*)out2 + (size_t)b*KROWS*192;
  for(int i = t; i < KROWS*192; i += 576){
    float v = (float)sidx[i/192];
    o4[i] = make_float4(v,v,v,v);
  }
}

extern "C" void kernel_launch(void* const* d_in, const int* in_sizes, int n_in,
                              void* d_out, int out_size, void* d_ws, size_t ws_size,
                              hipStream_t stream){
  const float* x     = (const float*)d_in[0];
  const float* Wqkv  = (const float*)d_in[1];
  const float* Wproj = (const float*)d_in[2];
  const float* bias  = (const float*)d_in[3];
  float* out  = (float*)d_out;
  float* out2 = out + (size_t)M_*768;      // keep_index chunk (float32)

  char* ws = (char*)d_ws;
  size_t off = 0;
  auto alloc = [&](size_t bytes)->void*{ void* p = ws + off; off += (bytes + 255) & ~(size_t)255; return p; };
  unsigned short* xb     = (unsigned short*)alloc((size_t)M_*768*2);
  unsigned short* wqkvT  = (unsigned short*)alloc((size_t)QKVN*768*2);
  unsigned short* wprojT = (unsigned short*)alloc((size_t)768*768*2);
  unsigned short* qkvb   = (unsigned short*)alloc((size_t)M_*QKVN*2);
  unsigned short* aoutb  = (unsigned short*)alloc((size_t)M_*768*2);
  unsigned short* vtbuf  = (unsigned short*)alloc((size_t)192*64*VTLD*2);
  float* qcls   = (float*)alloc((size_t)16*768*4);
  float* u      = (float*)alloc((size_t)16*12*768*4);
  float* attw   = (float*)alloc((size_t)16*577*4);

  // fused prep: cvt_x | transpose Wqkv | transpose Wproj | qcls  (7692 blocks)
  k_prep<<<7692, 256, 0, stream>>>(x, Wqkv, Wproj, xb, wqkvT, wprojT, qcls);
  // QKV GEMM (bf16 out; V-tiles transposed into vtbuf). BK=64 double-buffer, counted vmcnt.
  k_gemm_db<QKVN, true, true, 18><<<73*18, 256, 0, stream>>>(xb, wqkvT, qkvb, nullptr, M_, vtbuf);
  // fp32 top-k weight path
  k_u<<<dim3(12,16), 768, 0, stream>>>(Wqkv, qcls, u);
  k_attw<<<16*577, 64, 0, stream>>>(x, u, attw);
  k_topk_fill<<<16, 576, 0, stream>>>(attw, out2);
  // attention + out-proj (BK=64 single-buffer template)
  k_attn<<<960, 256, 0, stream>>>(qkvb, vtbuf, aoutb);
  k_gemm_bt_k64<768, false, false, 6><<<73*6, 256, 0, stream>>>(aoutb, wprojT, out, bias, M_, nullptr);
}